// Round 7
// baseline (538.567 us; speedup 1.0000x reference)
//
#include <hip/hip_runtime.h>

#define NN 100000
#define NE 1600000

// ---- degree count: 8 edges/thread for atomic MLP ----
__global__ void k_deg(const int* __restrict__ row, int* __restrict__ deg) {
    int base = blockIdx.x * 2048 + threadIdx.x;
    #pragma unroll
    for (int j = 0; j < 8; ++j) {
        int e = base + j * 256;
        if (e < NE) atomicAdd(&deg[row[e]], 1);
    }
}

__global__ void k_dinv(const int* __restrict__ deg, float* __restrict__ dinv) {
    int n = blockIdx.x * 256 + threadIdx.x;
    if (n < NN) {
        int d = deg[n];
        dinv[n] = d > 0 ? rsqrtf((float)d) : 0.0f;
    }
}

// ---- xs = x * dinv[node], float4 per thread ----
__global__ void k_scale(const float* __restrict__ x, const float* __restrict__ dinv,
                        float* __restrict__ xs) {
    int t = blockIdx.x * 256 + threadIdx.x;
    if (t < NN * 16) {
        float d = dinv[t >> 4];
        float4 v = ((const float4*)x)[t];
        v.x *= d; v.y *= d; v.z *= d; v.w *= d;
        ((float4*)xs)[t] = v;
    }
}

// ---- 3-kernel exclusive scan over deg -> row_ptr ----
__global__ void k_scan1(const int* __restrict__ deg, int* __restrict__ part, int* __restrict__ bsum) {
    __shared__ int s[256];
    int t = threadIdx.x, g = blockIdx.x * 256 + t;
    int d = (g < NN) ? deg[g] : 0;
    s[t] = d; __syncthreads();
    for (int off = 1; off < 256; off <<= 1) {
        int v = (t >= off) ? s[t - off] : 0;
        __syncthreads();
        s[t] += v;
        __syncthreads();
    }
    if (g < NN) part[g] = s[t] - d;
    if (t == 255) bsum[blockIdx.x] = s[t];
}

__global__ void k_scan2(int* __restrict__ bsum, int nb) {
    __shared__ int s[512];
    int t = threadIdx.x;
    int d = (t < nb) ? bsum[t] : 0;
    s[t] = d; __syncthreads();
    for (int off = 1; off < 512; off <<= 1) {
        int v = (t >= off) ? s[t - off] : 0;
        __syncthreads();
        s[t] += v;
        __syncthreads();
    }
    if (t < nb) bsum[t] = s[t] - d;
}

__global__ void k_scan3(const int* __restrict__ deg, const int* __restrict__ bsum,
                        int* __restrict__ row_ptr, int* __restrict__ cursor) {
    int g = blockIdx.x * 256 + threadIdx.x;
    if (g < NN) {
        int v = row_ptr[g] + bsum[g >> 8];
        row_ptr[g] = v;
        cursor[g] = v;
        if (g == NN - 1) row_ptr[NN] = v + deg[g];
    }
}

// ---- scatter: 8 independent atomic->store chains per thread ----
__global__ void k_scatter(const int* __restrict__ row, const int* __restrict__ col,
                          int* __restrict__ cursor, int* __restrict__ col_sorted) {
    int base = blockIdx.x * 2048 + threadIdx.x;
    int p[8], c[8];
    bool v[8];
    #pragma unroll
    for (int j = 0; j < 8; ++j) {
        int e = base + j * 256;
        v[j] = e < NE;
        if (v[j]) { c[j] = col[e]; p[j] = atomicAdd(&cursor[row[e]], 1); }
    }
    #pragma unroll
    for (int j = 0; j < 8; ++j)
        if (v[j]) col_sorted[p[j]] = c[j];
}

// ---- 64-wide SpMM on pre-scaled input: out[n] = -dinv[n]*sum_c ins[c]
//      has_sub: out = 2*out - sub; has_outs: outs = dinv[n]*out ----
__global__ __launch_bounds__(256) void k_spmm64(const float* __restrict__ ins, const float* __restrict__ sub,
                                                float* __restrict__ out, float* __restrict__ outs,
                                                const int* __restrict__ row_ptr, const int* __restrict__ cs,
                                                const float* __restrict__ dinv,
                                                int has_sub, int has_outs) {
    int n = blockIdx.x * 4 + (threadIdx.x >> 6);
    if (n >= NN) return;
    int nu = __builtin_amdgcn_readfirstlane(n);
    int lane = threadIdx.x & 63;
    int half = lane >> 5;
    int m = lane & 31;
    int s = row_ptr[nu], e = row_ptr[nu + 1];
    float ax0 = 0.f, ay0 = 0.f, ax1 = 0.f, ay1 = 0.f;
    float ax2 = 0.f, ay2 = 0.f, ax3 = 0.f, ay3 = 0.f;
    int i = s;
    // 8 edges per iteration: half-split (2) x unroll (4) -> 8 gathers in flight
    for (; i + 7 < e; i += 8) {
        int c0 = cs[i + half];
        int c1 = cs[i + 2 + half];
        int c2 = cs[i + 4 + half];
        int c3 = cs[i + 6 + half];
        float2 v0 = ((const float2*)(ins + (size_t)c0 * 64))[m];
        float2 v1 = ((const float2*)(ins + (size_t)c1 * 64))[m];
        float2 v2 = ((const float2*)(ins + (size_t)c2 * 64))[m];
        float2 v3 = ((const float2*)(ins + (size_t)c3 * 64))[m];
        ax0 += v0.x; ay0 += v0.y;
        ax1 += v1.x; ay1 += v1.y;
        ax2 += v2.x; ay2 += v2.y;
        ax3 += v3.x; ay3 += v3.y;
    }
    for (; i + 3 < e; i += 4) {
        int c0 = cs[i + half];
        int c1 = cs[i + 2 + half];
        float2 v0 = ((const float2*)(ins + (size_t)c0 * 64))[m];
        float2 v1 = ((const float2*)(ins + (size_t)c1 * 64))[m];
        ax0 += v0.x; ay0 += v0.y;
        ax1 += v1.x; ay1 += v1.y;
    }
    for (; i + 1 < e; i += 2) {
        int c = cs[i + half];
        float2 v = ((const float2*)(ins + (size_t)c * 64))[m];
        ax0 += v.x; ay0 += v.y;
    }
    if (i < e && half == 0) {
        int c = cs[i];
        float2 v = ((const float2*)(ins + (size_t)c * 64))[m];
        ax0 += v.x; ay0 += v.y;
    }
    float ax = (ax0 + ax1) + (ax2 + ax3);
    float ay = (ay0 + ay1) + (ay2 + ay3);
    ax += __shfl_xor(ax, 32);
    ay += __shfl_xor(ay, 32);
    if (half == 0) {
        float dn = dinv[nu];
        float rx = -dn * ax, ry = -dn * ay;
        if (has_sub) {
            float2 sv = ((const float2*)(sub + (size_t)nu * 64))[m];
            rx = 2.f * rx - sv.x;
            ry = 2.f * ry - sv.y;
        }
        float2 r; r.x = rx; r.y = ry;
        ((float2*)(out + (size_t)nu * 64))[m] = r;
        if (has_outs) {
            float2 rs; rs.x = dn * rx; rs.y = dn * ry;
            ((float2*)(outs + (size_t)nu * 64))[m] = rs;
        }
    }
}

// ---- dense layer 1: h = relu(x@W0 + t1@W1 + t2@W2 + b); wave = 8 nodes
//      W staged in LDS as bf16 (24 KB -> 6 blocks/CU, ~75% occupancy) ----
__global__ __launch_bounds__(256) void k_dense1(const float* __restrict__ x, const float* __restrict__ t1,
                                                const float* __restrict__ t2, const float* __restrict__ W,
                                                const float* __restrict__ b, float* __restrict__ h) {
    __shared__ unsigned short Ws[3 * 64 * 64];   // bf16 bits, 24576 B
    for (int i = threadIdx.x; i < 3 * 64 * 64; i += 256) {
        unsigned int u = __float_as_uint(W[i]);
        Ws[i] = (unsigned short)((u + 0x7FFFu + ((u >> 16) & 1u)) >> 16);   // RNE bf16
    }
    __syncthreads();
    int lane = threadIdx.x & 63;
    int n0 = __builtin_amdgcn_readfirstlane((blockIdx.x * 4 + (threadIdx.x >> 6)) * 8);
    if (n0 >= NN) return;
    float bl = b[lane];
    float acc[8];
    #pragma unroll
    for (int j = 0; j < 8; ++j) acc[j] = bl;
    const float* arrs[3] = {x, t1, t2};
    #pragma unroll
    for (int s3 = 0; s3 < 3; ++s3) {
        const float* A = arrs[s3] + (size_t)n0 * 64;
        const unsigned short* Wp = Ws + s3 * 4096;
        #pragma unroll 4
        for (int i = 0; i < 64; ++i) {
            float w = __uint_as_float((unsigned int)Wp[i * 64 + lane] << 16);
            #pragma unroll
            for (int j = 0; j < 8; ++j) acc[j] += A[j * 64 + i] * w;
        }
    }
    #pragma unroll
    for (int j = 0; j < 8; ++j)
        h[(size_t)(n0 + j) * 64 + lane] = fmaxf(acc[j], 0.f);
}

// ---- layer-2 projection: Apre = h@(W2[0]-W2[2]) + b2;  Gs = dinv*[h@W2[1] | h@W2[2]] ----
__global__ __launch_bounds__(256) void k_proj(const float* __restrict__ h, const float* __restrict__ W2,
                                              const float* __restrict__ b2, const float* __restrict__ dinv,
                                              float* __restrict__ Apre, float* __restrict__ Gs) {
    __shared__ float Wall[64 * 48];
    for (int i = threadIdx.x; i < 64 * 48; i += 256) {
        int r = i / 48, c = i % 48;
        float w;
        if (c < 16)       w = W2[r * 16 + c] - W2[2048 + r * 16 + c];
        else if (c < 32)  w = W2[1024 + r * 16 + (c - 16)];
        else              w = W2[2048 + r * 16 + (c - 32)];
        Wall[i] = w;
    }
    __syncthreads();
    int lane = threadIdx.x & 63;
    int cl = lane < 48 ? lane : 0;
    int n0 = __builtin_amdgcn_readfirstlane((blockIdx.x * 4 + (threadIdx.x >> 6)) * 8);
    if (n0 >= NN) return;
    float acc[8];
    #pragma unroll
    for (int j = 0; j < 8; ++j) acc[j] = 0.f;
    const float* A = h + (size_t)n0 * 64;
    #pragma unroll 4
    for (int i = 0; i < 64; ++i) {
        float w = Wall[i * 48 + cl];
        #pragma unroll
        for (int j = 0; j < 8; ++j) acc[j] += A[j * 64 + i] * w;
    }
    #pragma unroll
    for (int j = 0; j < 8; ++j) {
        int n = n0 + j;
        if (lane < 16) Apre[(size_t)n * 16 + lane] = acc[j] + b2[lane];
        else if (lane < 48) Gs[(size_t)n * 32 + (lane - 16)] = acc[j] * dinv[n];
    }
}

// ---- 32-wide fused SpMM: q1 = P(g1); ts = dinv * P(g2) ----
__global__ __launch_bounds__(256) void k_spmm32(const float* __restrict__ Gs, float* __restrict__ q1,
                                                float* __restrict__ ts, const int* __restrict__ row_ptr,
                                                const int* __restrict__ cs, const float* __restrict__ dinv) {
    int n = blockIdx.x * 4 + (threadIdx.x >> 6);
    if (n >= NN) return;
    int nu = __builtin_amdgcn_readfirstlane(n);
    int lane = threadIdx.x & 63;
    int es = lane >> 5;      // 2 edges in parallel
    int f = lane & 31;
    int s = row_ptr[nu], e = row_ptr[nu + 1];
    float a0 = 0.f, a1 = 0.f;
    int i = s;
    for (; i + 3 < e; i += 4) {
        int c0 = cs[i + es];
        int c1 = cs[i + 2 + es];
        a0 += Gs[(size_t)c0 * 32 + f];
        a1 += Gs[(size_t)c1 * 32 + f];
    }
    for (; i + 1 < e; i += 2) {
        a0 += Gs[(size_t)cs[i + es] * 32 + f];
    }
    if (i < e && es == 0) a0 += Gs[(size_t)cs[i] * 32 + f];
    float a = a0 + a1;
    a += __shfl_xor(a, 32);
    if (es == 0) {
        float dn = dinv[nu];
        float v = -dn * a;
        if (f < 16) q1[(size_t)nu * 16 + f] = v;
        else        ts[(size_t)nu * 16 + (f - 16)] = dn * v;
    }
}

// ---- 16-wide SpMM + final combine + log_softmax ----
__global__ __launch_bounds__(256) void k_spmm16f(const float* __restrict__ ts, const float* __restrict__ Apre,
                                                 const float* __restrict__ q1, const int* __restrict__ row_ptr,
                                                 const int* __restrict__ cs, const float* __restrict__ dinv,
                                                 float* __restrict__ out) {
    int n = blockIdx.x * 4 + (threadIdx.x >> 6);
    if (n >= NN) return;
    int nu = __builtin_amdgcn_readfirstlane(n);
    int lane = threadIdx.x & 63;
    int es = lane >> 4;      // 4 edges in parallel
    int f = lane & 15;
    int s = row_ptr[nu], e = row_ptr[nu + 1];
    float a0 = 0.f, a1 = 0.f;
    int i = s;
    for (; i + 7 < e; i += 8) {
        int c0 = cs[i + es];
        int c1 = cs[i + 4 + es];
        a0 += ts[(size_t)c0 * 16 + f];
        a1 += ts[(size_t)c1 * 16 + f];
    }
    for (; i + 3 < e; i += 4) {
        a0 += ts[(size_t)cs[i + es] * 16 + f];
    }
    if (i + es < e) a0 += ts[(size_t)cs[i + es] * 16 + f];
    float a = a0 + a1;
    a += __shfl_xor(a, 16);
    a += __shfl_xor(a, 32);
    if (es == 0) {
        float dn = dinv[nu];
        float r = -dn * a;
        float o = Apre[(size_t)nu * 16 + f] + q1[(size_t)nu * 16 + f] + 2.f * r;
        float m = o;
        for (int off = 1; off < 16; off <<= 1) m = fmaxf(m, __shfl_xor(m, off, 16));
        float ex = expf(o - m);
        float ssum = ex;
        for (int off = 1; off < 16; off <<= 1) ssum += __shfl_xor(ssum, off, 16);
        out[(size_t)nu * 16 + f] = o - m - logf(ssum);
    }
}

extern "C" void kernel_launch(void* const* d_in, const int* in_sizes, int n_in,
                              void* d_out, int out_size, void* d_ws, size_t ws_size,
                              hipStream_t stream) {
    const float* x  = (const float*)d_in[0];
    const int*   ei = (const int*)d_in[1];
    const int*   row = ei;
    const int*   col = ei + NE;
    const float* W1 = (const float*)d_in[2];
    const float* b1 = (const float*)d_in[3];
    const float* W2 = (const float*)d_in[4];
    const float* b2 = (const float*)d_in[5];
    float* out = (float*)d_out;

    char* base = (char*)d_ws;
    size_t off = 0;
    auto alloc = [&](size_t bytes) -> char* {
        char* r = base + off;
        off = (off + bytes + 255) & ~(size_t)255;
        return r;
    };
    int*   deg        = (int*)alloc((size_t)NN * 4);
    float* dinv       = (float*)alloc((size_t)NN * 4);
    int*   row_ptr    = (int*)alloc((size_t)(NN + 1) * 4);
    int*   cursor     = (int*)alloc((size_t)NN * 4);
    int*   bsum       = (int*)alloc(512 * 4);
    int*   col_sorted = (int*)alloc((size_t)NE * 4);
    float* XS         = (float*)alloc((size_t)NN * 64 * 4);
    float* T1         = (float*)alloc((size_t)NN * 64 * 4);
    float* T1s        = (float*)alloc((size_t)NN * 64 * 4);
    float* T2         = (float*)alloc((size_t)NN * 64 * 4);
    float* H          = (float*)alloc((size_t)NN * 64 * 4);
    float* Apre       = (float*)alloc((size_t)NN * 16 * 4);
    float* Gs         = (float*)alloc((size_t)NN * 32 * 4);
    float* q1         = (float*)alloc((size_t)NN * 16 * 4);
    float* ts         = (float*)alloc((size_t)NN * 16 * 4);

    hipMemsetAsync(deg, 0, (size_t)NN * 4, stream);

    int nbN  = (NN + 255) / 256;
    int nbE8 = (NE + 2047) / 2048;
    k_deg<<<nbE8, 256, 0, stream>>>(row, deg);
    k_dinv<<<nbN, 256, 0, stream>>>(deg, dinv);
    k_scale<<<(NN * 16 + 255) / 256, 256, 0, stream>>>(x, dinv, XS);
    k_scan1<<<nbN, 256, 0, stream>>>(deg, row_ptr, bsum);
    k_scan2<<<1, 512, 0, stream>>>(bsum, nbN);
    k_scan3<<<nbN, 256, 0, stream>>>(deg, bsum, row_ptr, cursor);
    k_scatter<<<nbE8, 256, 0, stream>>>(row, col, cursor, col_sorted);

    int nbS = (NN + 3) / 4;   // wave per node
    // layer 1
    k_spmm64<<<nbS, 256, 0, stream>>>(XS, nullptr, T1, T1s, row_ptr, col_sorted, dinv, 0, 1);
    k_spmm64<<<nbS, 256, 0, stream>>>(T1s, x, T2, nullptr, row_ptr, col_sorted, dinv, 1, 0);
    k_dense1<<<3125, 256, 0, stream>>>(x, T1, T2, W1, b1, H);
    // layer 2: project to 16-wide first, then narrow propagations
    k_proj<<<3125, 256, 0, stream>>>(H, W2, b2, dinv, Apre, Gs);
    k_spmm32<<<nbS, 256, 0, stream>>>(Gs, q1, ts, row_ptr, col_sorted, dinv);
    k_spmm16f<<<nbS, 256, 0, stream>>>(ts, Apre, q1, row_ptr, col_sorted, dinv, out);
}

// Round 8
// 470.894 us; speedup vs baseline: 1.1437x; 1.1437x over previous
//
#include <hip/hip_runtime.h>

#define NN 100000
#define NE 1600000

typedef __attribute__((ext_vector_type(8))) short bf16x8;
typedef __attribute__((ext_vector_type(4))) float f32x4;

__device__ inline unsigned short f2bf(float f) {
    unsigned int u = __float_as_uint(f);
    return (unsigned short)((u + 0x7FFFu + ((u >> 16) & 1u)) >> 16);   // RNE bf16
}

// ---- degree count: 8 edges/thread for atomic MLP ----
__global__ void k_deg(const int* __restrict__ row, int* __restrict__ deg) {
    int base = blockIdx.x * 2048 + threadIdx.x;
    #pragma unroll
    for (int j = 0; j < 8; ++j) {
        int e = base + j * 256;
        if (e < NE) atomicAdd(&deg[row[e]], 1);
    }
}

__global__ void k_dinv(const int* __restrict__ deg, float* __restrict__ dinv) {
    int n = blockIdx.x * 256 + threadIdx.x;
    if (n < NN) {
        int d = deg[n];
        dinv[n] = d > 0 ? rsqrtf((float)d) : 0.0f;
    }
}

// ---- xs = x * dinv[node], float4 per thread ----
__global__ void k_scale(const float* __restrict__ x, const float* __restrict__ dinv,
                        float* __restrict__ xs) {
    int t = blockIdx.x * 256 + threadIdx.x;
    if (t < NN * 16) {
        float d = dinv[t >> 4];
        float4 v = ((const float4*)x)[t];
        v.x *= d; v.y *= d; v.z *= d; v.w *= d;
        ((float4*)xs)[t] = v;
    }
}

// ---- 3-kernel exclusive scan over deg -> row_ptr ----
__global__ void k_scan1(const int* __restrict__ deg, int* __restrict__ part, int* __restrict__ bsum) {
    __shared__ int s[256];
    int t = threadIdx.x, g = blockIdx.x * 256 + t;
    int d = (g < NN) ? deg[g] : 0;
    s[t] = d; __syncthreads();
    for (int off = 1; off < 256; off <<= 1) {
        int v = (t >= off) ? s[t - off] : 0;
        __syncthreads();
        s[t] += v;
        __syncthreads();
    }
    if (g < NN) part[g] = s[t] - d;
    if (t == 255) bsum[blockIdx.x] = s[t];
}

__global__ void k_scan2(int* __restrict__ bsum, int nb) {
    __shared__ int s[512];
    int t = threadIdx.x;
    int d = (t < nb) ? bsum[t] : 0;
    s[t] = d; __syncthreads();
    for (int off = 1; off < 512; off <<= 1) {
        int v = (t >= off) ? s[t - off] : 0;
        __syncthreads();
        s[t] += v;
        __syncthreads();
    }
    if (t < nb) bsum[t] = s[t] - d;
}

__global__ void k_scan3(const int* __restrict__ deg, const int* __restrict__ bsum,
                        int* __restrict__ row_ptr, int* __restrict__ cursor) {
    int g = blockIdx.x * 256 + threadIdx.x;
    if (g < NN) {
        int v = row_ptr[g] + bsum[g >> 8];
        row_ptr[g] = v;
        cursor[g] = v;
        if (g == NN - 1) row_ptr[NN] = v + deg[g];
    }
}

// ---- scatter: 8 independent atomic->store chains per thread ----
__global__ void k_scatter(const int* __restrict__ row, const int* __restrict__ col,
                          int* __restrict__ cursor, int* __restrict__ col_sorted) {
    int base = blockIdx.x * 2048 + threadIdx.x;
    int p[8], c[8];
    bool v[8];
    #pragma unroll
    for (int j = 0; j < 8; ++j) {
        int e = base + j * 256;
        v[j] = e < NE;
        if (v[j]) { c[j] = col[e]; p[j] = atomicAdd(&cursor[row[e]], 1); }
    }
    #pragma unroll
    for (int j = 0; j < 8; ++j)
        if (v[j]) col_sorted[p[j]] = c[j];
}

// ---- 64-wide SpMM on pre-scaled input ----
__global__ __launch_bounds__(256) void k_spmm64(const float* __restrict__ ins, const float* __restrict__ sub,
                                                float* __restrict__ out, float* __restrict__ outs,
                                                const int* __restrict__ row_ptr, const int* __restrict__ cs,
                                                const float* __restrict__ dinv,
                                                int has_sub, int has_outs) {
    int n = blockIdx.x * 4 + (threadIdx.x >> 6);
    if (n >= NN) return;
    int nu = __builtin_amdgcn_readfirstlane(n);
    int lane = threadIdx.x & 63;
    int half = lane >> 5;
    int m = lane & 31;
    int s = row_ptr[nu], e = row_ptr[nu + 1];
    float ax0 = 0.f, ay0 = 0.f, ax1 = 0.f, ay1 = 0.f;
    float ax2 = 0.f, ay2 = 0.f, ax3 = 0.f, ay3 = 0.f;
    int i = s;
    for (; i + 7 < e; i += 8) {
        int c0 = cs[i + half];
        int c1 = cs[i + 2 + half];
        int c2 = cs[i + 4 + half];
        int c3 = cs[i + 6 + half];
        float2 v0 = ((const float2*)(ins + (size_t)c0 * 64))[m];
        float2 v1 = ((const float2*)(ins + (size_t)c1 * 64))[m];
        float2 v2 = ((const float2*)(ins + (size_t)c2 * 64))[m];
        float2 v3 = ((const float2*)(ins + (size_t)c3 * 64))[m];
        ax0 += v0.x; ay0 += v0.y;
        ax1 += v1.x; ay1 += v1.y;
        ax2 += v2.x; ay2 += v2.y;
        ax3 += v3.x; ay3 += v3.y;
    }
    for (; i + 3 < e; i += 4) {
        int c0 = cs[i + half];
        int c1 = cs[i + 2 + half];
        float2 v0 = ((const float2*)(ins + (size_t)c0 * 64))[m];
        float2 v1 = ((const float2*)(ins + (size_t)c1 * 64))[m];
        ax0 += v0.x; ay0 += v0.y;
        ax1 += v1.x; ay1 += v1.y;
    }
    for (; i + 1 < e; i += 2) {
        int c = cs[i + half];
        float2 v = ((const float2*)(ins + (size_t)c * 64))[m];
        ax0 += v.x; ay0 += v.y;
    }
    if (i < e && half == 0) {
        int c = cs[i];
        float2 v = ((const float2*)(ins + (size_t)c * 64))[m];
        ax0 += v.x; ay0 += v.y;
    }
    float ax = (ax0 + ax1) + (ax2 + ax3);
    float ay = (ay0 + ay1) + (ay2 + ay3);
    ax += __shfl_xor(ax, 32);
    ay += __shfl_xor(ay, 32);
    if (half == 0) {
        float dn = dinv[nu];
        float rx = -dn * ax, ry = -dn * ay;
        if (has_sub) {
            float2 sv = ((const float2*)(sub + (size_t)nu * 64))[m];
            rx = 2.f * rx - sv.x;
            ry = 2.f * ry - sv.y;
        }
        float2 r; r.x = rx; r.y = ry;
        ((float2*)(out + (size_t)nu * 64))[m] = r;
        if (has_outs) {
            float2 rs; rs.x = dn * rx; rs.y = dn * ry;
            ((float2*)(outs + (size_t)nu * 64))[m] = rs;
        }
    }
}

// ---- dense layer 1 via MFMA: h = relu([x|t1|t2] @ W + b)
//      M=16-node tiles, N=64 (4 col-tiles), K=192 (6 k-steps of 32)
//      B (weights) packed once/block into LDS as lane-ordered bf16 frags,
//      then register-resident per wave; A rows: float4 loads + RNE->bf16 ----
__global__ __launch_bounds__(256) void k_dense1(const float* __restrict__ x, const float* __restrict__ t1,
                                                const float* __restrict__ t2, const float* __restrict__ W,
                                                const float* __restrict__ b, float* __restrict__ h) {
    __shared__ unsigned short Wf[24 * 64 * 8];   // [c*6+t][lane][8 bf16] = 24576 B
    // phase 1: cooperative fragment pack (c,t,lane) -> 8 bf16
    for (int slot = threadIdx.x; slot < 24 * 64; slot += 256) {
        int c = slot / 384;
        int t = (slot / 64) % 6;
        int l = slot & 63;
        int rr = l & 15, gg = l >> 4;
        unsigned int pk[4];
        #pragma unroll
        for (int jp = 0; jp < 4; ++jp) {
            int k0 = t * 32 + gg * 8 + jp * 2;
            unsigned int lo = f2bf(W[(k0 >> 6) * 4096 + (k0 & 63) * 64 + c * 16 + rr]);
            int k1 = k0 + 1;
            unsigned int hi = f2bf(W[(k1 >> 6) * 4096 + (k1 & 63) * 64 + c * 16 + rr]);
            pk[jp] = lo | (hi << 16);
        }
        *((uint4*)&Wf[slot * 8]) = *((uint4*)pk);
    }
    __syncthreads();

    int lane = threadIdx.x & 63;
    int r = lane & 15, g = lane >> 4;
    // phase 2: B frags -> registers (24 x ds_read_b128)
    bf16x8 bfr[4][6];
    #pragma unroll
    for (int c = 0; c < 4; ++c)
        #pragma unroll
        for (int t = 0; t < 6; ++t)
            bfr[c][t] = *((const bf16x8*)&Wf[((c * 6 + t) * 64 + lane) * 8]);

    float bl[4];
    #pragma unroll
    for (int c = 0; c < 4; ++c) bl[c] = b[c * 16 + r];

    const float* arrs[3] = {x, t1, t2};
    int wid = blockIdx.x * 4 + (threadIdx.x >> 6);
    int wstride = gridDim.x * 4;
    // phase 3: grid-stride over 16-node tiles
    for (int tile = wid; tile < NN / 16; tile += wstride) {
        int nb = tile * 16;
        bf16x8 af[6];
        #pragma unroll
        for (int t = 0; t < 6; ++t) {
            const float* A = arrs[t >> 1] + (size_t)(nb + r) * 64 + (t & 1) * 32 + g * 8;
            float4 v0 = *((const float4*)A);
            float4 v1 = *((const float4*)(A + 4));
            af[t][0] = (short)f2bf(v0.x); af[t][1] = (short)f2bf(v0.y);
            af[t][2] = (short)f2bf(v0.z); af[t][3] = (short)f2bf(v0.w);
            af[t][4] = (short)f2bf(v1.x); af[t][5] = (short)f2bf(v1.y);
            af[t][6] = (short)f2bf(v1.z); af[t][7] = (short)f2bf(v1.w);
        }
        f32x4 acc[4];
        #pragma unroll
        for (int c = 0; c < 4; ++c) acc[c] = (f32x4){bl[c], bl[c], bl[c], bl[c]};
        #pragma unroll
        for (int t = 0; t < 6; ++t)
            #pragma unroll
            for (int c = 0; c < 4; ++c)
                acc[c] = __builtin_amdgcn_mfma_f32_16x16x32_bf16(af[t], bfr[c][t], acc[c], 0, 0, 0);
        // D: col = lane&15 (out feature within tile), row = (lane>>4)*4 + q (node)
        #pragma unroll
        for (int c = 0; c < 4; ++c)
            #pragma unroll
            for (int q = 0; q < 4; ++q)
                h[(size_t)(nb + g * 4 + q) * 64 + c * 16 + r] = fmaxf(acc[c][q], 0.f);
    }
}

// ---- layer-2 projection: Apre = h@(W2[0]-W2[2]) + b2;  Gs = dinv*[h@W2[1] | h@W2[2]] ----
__global__ __launch_bounds__(256) void k_proj(const float* __restrict__ h, const float* __restrict__ W2,
                                              const float* __restrict__ b2, const float* __restrict__ dinv,
                                              float* __restrict__ Apre, float* __restrict__ Gs) {
    __shared__ float Wall[64 * 48];
    for (int i = threadIdx.x; i < 64 * 48; i += 256) {
        int r = i / 48, c = i % 48;
        float w;
        if (c < 16)       w = W2[r * 16 + c] - W2[2048 + r * 16 + c];
        else if (c < 32)  w = W2[1024 + r * 16 + (c - 16)];
        else              w = W2[2048 + r * 16 + (c - 32)];
        Wall[i] = w;
    }
    __syncthreads();
    int lane = threadIdx.x & 63;
    int cl = lane < 48 ? lane : 0;
    int n0 = __builtin_amdgcn_readfirstlane((blockIdx.x * 4 + (threadIdx.x >> 6)) * 8);
    if (n0 >= NN) return;
    float acc[8];
    #pragma unroll
    for (int j = 0; j < 8; ++j) acc[j] = 0.f;
    const float* A = h + (size_t)n0 * 64;
    #pragma unroll 4
    for (int i = 0; i < 64; ++i) {
        float w = Wall[i * 48 + cl];
        #pragma unroll
        for (int j = 0; j < 8; ++j) acc[j] += A[j * 64 + i] * w;
    }
    #pragma unroll
    for (int j = 0; j < 8; ++j) {
        int n = n0 + j;
        if (lane < 16) Apre[(size_t)n * 16 + lane] = acc[j] + b2[lane];
        else if (lane < 48) Gs[(size_t)n * 32 + (lane - 16)] = acc[j] * dinv[n];
    }
}

// ---- 32-wide fused SpMM: q1 = P(g1); ts = dinv * P(g2) ----
__global__ __launch_bounds__(256) void k_spmm32(const float* __restrict__ Gs, float* __restrict__ q1,
                                                float* __restrict__ ts, const int* __restrict__ row_ptr,
                                                const int* __restrict__ cs, const float* __restrict__ dinv) {
    int n = blockIdx.x * 4 + (threadIdx.x >> 6);
    if (n >= NN) return;
    int nu = __builtin_amdgcn_readfirstlane(n);
    int lane = threadIdx.x & 63;
    int es = lane >> 5;
    int f = lane & 31;
    int s = row_ptr[nu], e = row_ptr[nu + 1];
    float a0 = 0.f, a1 = 0.f;
    int i = s;
    for (; i + 3 < e; i += 4) {
        int c0 = cs[i + es];
        int c1 = cs[i + 2 + es];
        a0 += Gs[(size_t)c0 * 32 + f];
        a1 += Gs[(size_t)c1 * 32 + f];
    }
    for (; i + 1 < e; i += 2) {
        a0 += Gs[(size_t)cs[i + es] * 32 + f];
    }
    if (i < e && es == 0) a0 += Gs[(size_t)cs[i] * 32 + f];
    float a = a0 + a1;
    a += __shfl_xor(a, 32);
    if (es == 0) {
        float dn = dinv[nu];
        float v = -dn * a;
        if (f < 16) q1[(size_t)nu * 16 + f] = v;
        else        ts[(size_t)nu * 16 + (f - 16)] = dn * v;
    }
}

// ---- 16-wide SpMM + final combine + log_softmax ----
__global__ __launch_bounds__(256) void k_spmm16f(const float* __restrict__ ts, const float* __restrict__ Apre,
                                                 const float* __restrict__ q1, const int* __restrict__ row_ptr,
                                                 const int* __restrict__ cs, const float* __restrict__ dinv,
                                                 float* __restrict__ out) {
    int n = blockIdx.x * 4 + (threadIdx.x >> 6);
    if (n >= NN) return;
    int nu = __builtin_amdgcn_readfirstlane(n);
    int lane = threadIdx.x & 63;
    int es = lane >> 4;
    int f = lane & 15;
    int s = row_ptr[nu], e = row_ptr[nu + 1];
    float a0 = 0.f, a1 = 0.f;
    int i = s;
    for (; i + 7 < e; i += 8) {
        int c0 = cs[i + es];
        int c1 = cs[i + 4 + es];
        a0 += ts[(size_t)c0 * 16 + f];
        a1 += ts[(size_t)c1 * 16 + f];
    }
    for (; i + 3 < e; i += 4) {
        a0 += ts[(size_t)cs[i + es] * 16 + f];
    }
    if (i + es < e) a0 += ts[(size_t)cs[i + es] * 16 + f];
    float a = a0 + a1;
    a += __shfl_xor(a, 16);
    a += __shfl_xor(a, 32);
    if (es == 0) {
        float dn = dinv[nu];
        float r = -dn * a;
        float o = Apre[(size_t)nu * 16 + f] + q1[(size_t)nu * 16 + f] + 2.f * r;
        float m = o;
        for (int off = 1; off < 16; off <<= 1) m = fmaxf(m, __shfl_xor(m, off, 16));
        float ex = expf(o - m);
        float ssum = ex;
        for (int off = 1; off < 16; off <<= 1) ssum += __shfl_xor(ssum, off, 16);
        out[(size_t)nu * 16 + f] = o - m - logf(ssum);
    }
}

extern "C" void kernel_launch(void* const* d_in, const int* in_sizes, int n_in,
                              void* d_out, int out_size, void* d_ws, size_t ws_size,
                              hipStream_t stream) {
    const float* x  = (const float*)d_in[0];
    const int*   ei = (const int*)d_in[1];
    const int*   row = ei;
    const int*   col = ei + NE;
    const float* W1 = (const float*)d_in[2];
    const float* b1 = (const float*)d_in[3];
    const float* W2 = (const float*)d_in[4];
    const float* b2 = (const float*)d_in[5];
    float* out = (float*)d_out;

    char* base = (char*)d_ws;
    size_t off = 0;
    auto alloc = [&](size_t bytes) -> char* {
        char* r = base + off;
        off = (off + bytes + 255) & ~(size_t)255;
        return r;
    };
    int*   deg        = (int*)alloc((size_t)NN * 4);
    float* dinv       = (float*)alloc((size_t)NN * 4);
    int*   row_ptr    = (int*)alloc((size_t)(NN + 1) * 4);
    int*   cursor     = (int*)alloc((size_t)NN * 4);
    int*   bsum       = (int*)alloc(512 * 4);
    int*   col_sorted = (int*)alloc((size_t)NE * 4);
    float* XS         = (float*)alloc((size_t)NN * 64 * 4);
    float* T1         = (float*)alloc((size_t)NN * 64 * 4);
    float* T1s        = (float*)alloc((size_t)NN * 64 * 4);
    float* T2         = (float*)alloc((size_t)NN * 64 * 4);
    float* H          = (float*)alloc((size_t)NN * 64 * 4);
    float* Apre       = (float*)alloc((size_t)NN * 16 * 4);
    float* Gs         = (float*)alloc((size_t)NN * 32 * 4);
    float* q1         = (float*)alloc((size_t)NN * 16 * 4);
    float* ts         = (float*)alloc((size_t)NN * 16 * 4);

    hipMemsetAsync(deg, 0, (size_t)NN * 4, stream);

    int nbN  = (NN + 255) / 256;
    int nbE8 = (NE + 2047) / 2048;
    k_deg<<<nbE8, 256, 0, stream>>>(row, deg);
    k_dinv<<<nbN, 256, 0, stream>>>(deg, dinv);
    k_scale<<<(NN * 16 + 255) / 256, 256, 0, stream>>>(x, dinv, XS);
    k_scan1<<<nbN, 256, 0, stream>>>(deg, row_ptr, bsum);
    k_scan2<<<1, 512, 0, stream>>>(bsum, nbN);
    k_scan3<<<nbN, 256, 0, stream>>>(deg, bsum, row_ptr, cursor);
    k_scatter<<<nbE8, 256, 0, stream>>>(row, col, cursor, col_sorted);

    int nbS = (NN + 3) / 4;   // wave per node
    // layer 1
    k_spmm64<<<nbS, 256, 0, stream>>>(XS, nullptr, T1, T1s, row_ptr, col_sorted, dinv, 0, 1);
    k_spmm64<<<nbS, 256, 0, stream>>>(T1s, x, T2, nullptr, row_ptr, col_sorted, dinv, 1, 0);
    k_dense1<<<521, 256, 0, stream>>>(x, T1, T2, W1, b1, H);
    // layer 2: project to 16-wide first, then narrow propagations
    k_proj<<<3125, 256, 0, stream>>>(H, W2, b2, dinv, Apre, Gs);
    k_spmm32<<<nbS, 256, 0, stream>>>(Gs, q1, ts, row_ptr, col_sorted, dinv);
    k_spmm16f<<<nbS, 256, 0, stream>>>(ts, Apre, q1, row_ptr, col_sorted, dinv, out);
}

// Round 9
// 309.219 us; speedup vs baseline: 1.7417x; 1.5228x over previous
//
#include <hip/hip_runtime.h>

#define NN 100000
#define NE 1600000

typedef __attribute__((ext_vector_type(8))) short bf16x8;
typedef __attribute__((ext_vector_type(4))) short bf16x4;
typedef __attribute__((ext_vector_type(2))) short bf16x2;
typedef __attribute__((ext_vector_type(4))) float f32x4;

__device__ inline unsigned short f2bf(float f) {
    unsigned int u = __float_as_uint(f);
    return (unsigned short)((u + 0x7FFFu + ((u >> 16) & 1u)) >> 16);   // RNE bf16
}
__device__ inline float bf2f(short s) {
    return __uint_as_float(((unsigned int)(unsigned short)s) << 16);
}

// ---- degree + rank: rank[e] = old count. 8 chains/thread; atomic->coalesced store ----
__global__ void k_degrank(const int* __restrict__ row, int* __restrict__ deg, int* __restrict__ rank) {
    int base = blockIdx.x * 2048 + threadIdx.x;
    #pragma unroll
    for (int j = 0; j < 8; ++j) {
        int e = base + j * 256;
        if (e < NE) rank[e] = atomicAdd(&deg[row[e]], 1);
    }
}

__global__ void k_dinv(const int* __restrict__ deg, float* __restrict__ dinv) {
    int n = blockIdx.x * 256 + threadIdx.x;
    if (n < NN) {
        int d = deg[n];
        dinv[n] = d > 0 ? rsqrtf((float)d) : 0.0f;
    }
}

// ---- bf16 copies: xbf = bf16(x), xsbf = bf16(x*dinv) ----
__global__ void k_scale(const float* __restrict__ x, const float* __restrict__ dinv,
                        unsigned short* __restrict__ xsbf, unsigned short* __restrict__ xbf) {
    int t = blockIdx.x * 256 + threadIdx.x;
    if (t < NN * 16) {
        float d = dinv[t >> 4];
        float4 v = ((const float4*)x)[t];
        bf16x4 u, s;
        u[0] = (short)f2bf(v.x); u[1] = (short)f2bf(v.y); u[2] = (short)f2bf(v.z); u[3] = (short)f2bf(v.w);
        s[0] = (short)f2bf(v.x * d); s[1] = (short)f2bf(v.y * d); s[2] = (short)f2bf(v.z * d); s[3] = (short)f2bf(v.w * d);
        ((bf16x4*)xbf)[t] = u;
        ((bf16x4*)xsbf)[t] = s;
    }
}

// ---- 3-kernel exclusive scan over deg -> row_ptr ----
__global__ void k_scan1(const int* __restrict__ deg, int* __restrict__ part, int* __restrict__ bsum) {
    __shared__ int s[256];
    int t = threadIdx.x, g = blockIdx.x * 256 + t;
    int d = (g < NN) ? deg[g] : 0;
    s[t] = d; __syncthreads();
    for (int off = 1; off < 256; off <<= 1) {
        int v = (t >= off) ? s[t - off] : 0;
        __syncthreads();
        s[t] += v;
        __syncthreads();
    }
    if (g < NN) part[g] = s[t] - d;
    if (t == 255) bsum[blockIdx.x] = s[t];
}

__global__ void k_scan2(int* __restrict__ bsum, int nb) {
    __shared__ int s[512];
    int t = threadIdx.x;
    int d = (t < nb) ? bsum[t] : 0;
    s[t] = d; __syncthreads();
    for (int off = 1; off < 512; off <<= 1) {
        int v = (t >= off) ? s[t - off] : 0;
        __syncthreads();
        s[t] += v;
        __syncthreads();
    }
    if (t < nb) bsum[t] = s[t] - d;
}

__global__ void k_scan3(const int* __restrict__ deg, const int* __restrict__ bsum,
                        int* __restrict__ row_ptr) {
    int g = blockIdx.x * 256 + threadIdx.x;
    if (g < NN) {
        int v = row_ptr[g] + bsum[g >> 8];
        row_ptr[g] = v;
        if (g == NN - 1) row_ptr[NN] = v + deg[g];
    }
}

// ---- place: no atomics, pure-throughput random store ----
__global__ void k_place(const int* __restrict__ row, const int* __restrict__ col,
                        const int* __restrict__ rank, const int* __restrict__ row_ptr,
                        int* __restrict__ col_sorted) {
    int base = blockIdx.x * 2048 + threadIdx.x;
    #pragma unroll
    for (int j = 0; j < 8; ++j) {
        int e = base + j * 256;
        if (e < NE) col_sorted[row_ptr[row[e]] + rank[e]] = col[e];
    }
}

// ---- 64-wide bf16 SpMM: out[n] = -dinv[n]*sum_c ins[c] (+Cheb sub), bf16 in/out, f32 accum
//      quarter-wave split: 4 edges in parallel, 8B/lane gathers, unroll 2 -> 8 in flight ----
__global__ __launch_bounds__(256) void k_spmm64b(const unsigned short* __restrict__ ins,
                                                 const float* __restrict__ sub,
                                                 unsigned short* __restrict__ outb,
                                                 unsigned short* __restrict__ outsb,
                                                 const int* __restrict__ row_ptr, const int* __restrict__ cs,
                                                 const float* __restrict__ dinv,
                                                 int has_sub, int has_outs) {
    int n = blockIdx.x * 4 + (threadIdx.x >> 6);
    if (n >= NN) return;
    int nu = __builtin_amdgcn_readfirstlane(n);
    int lane = threadIdx.x & 63;
    int qs = lane >> 4;     // edge slot 0..3
    int f = lane & 15;      // features 4f..4f+3
    int s = row_ptr[nu], e = row_ptr[nu + 1];
    float a0[4] = {0.f, 0.f, 0.f, 0.f}, a1[4] = {0.f, 0.f, 0.f, 0.f};
    int i = s;
    for (; i + 7 < e; i += 8) {
        int c0 = cs[i + qs];
        int c1 = cs[i + 4 + qs];
        bf16x4 v0 = *((const bf16x4*)(ins + (size_t)c0 * 64 + f * 4));
        bf16x4 v1 = *((const bf16x4*)(ins + (size_t)c1 * 64 + f * 4));
        #pragma unroll
        for (int j = 0; j < 4; ++j) { a0[j] += bf2f(v0[j]); a1[j] += bf2f(v1[j]); }
    }
    for (; i + 3 < e; i += 4) {
        int c0 = cs[i + qs];
        bf16x4 v0 = *((const bf16x4*)(ins + (size_t)c0 * 64 + f * 4));
        #pragma unroll
        for (int j = 0; j < 4; ++j) a0[j] += bf2f(v0[j]);
    }
    if (i + qs < e) {
        int c0 = cs[i + qs];
        bf16x4 v0 = *((const bf16x4*)(ins + (size_t)c0 * 64 + f * 4));
        #pragma unroll
        for (int j = 0; j < 4; ++j) a0[j] += bf2f(v0[j]);
    }
    float a[4];
    #pragma unroll
    for (int j = 0; j < 4; ++j) {
        a[j] = a0[j] + a1[j];
        a[j] += __shfl_xor(a[j], 16);
        a[j] += __shfl_xor(a[j], 32);
    }
    if (qs == 0) {
        float dn = dinv[nu];
        float r[4];
        #pragma unroll
        for (int j = 0; j < 4; ++j) r[j] = -dn * a[j];
        if (has_sub) {
            float4 sv = *((const float4*)(sub + (size_t)nu * 64 + f * 4));
            r[0] = 2.f * r[0] - sv.x; r[1] = 2.f * r[1] - sv.y;
            r[2] = 2.f * r[2] - sv.z; r[3] = 2.f * r[3] - sv.w;
        }
        bf16x4 ob;
        #pragma unroll
        for (int j = 0; j < 4; ++j) ob[j] = (short)f2bf(r[j]);
        *((bf16x4*)(outb + (size_t)nu * 64 + f * 4)) = ob;
        if (has_outs) {
            bf16x4 os;
            #pragma unroll
            for (int j = 0; j < 4; ++j) os[j] = (short)f2bf(dn * r[j]);
            *((bf16x4*)(outsb + (size_t)nu * 64 + f * 4)) = os;
        }
    }
}

// ---- dense layer 1 via MFMA: hbf = relu([x|t1|t2] @ W + b), all-bf16 A stream ----
__global__ __launch_bounds__(256) void k_dense1(const unsigned short* __restrict__ xbf,
                                                const unsigned short* __restrict__ t1bf,
                                                const unsigned short* __restrict__ t2bf,
                                                const float* __restrict__ W,
                                                const float* __restrict__ b,
                                                unsigned short* __restrict__ hbf) {
    __shared__ unsigned short Wf[24 * 64 * 8];   // [c*6+t][lane][8 bf16]
    for (int slot = threadIdx.x; slot < 24 * 64; slot += 256) {
        int c = slot / 384;
        int t = (slot / 64) % 6;
        int l = slot & 63;
        int rr = l & 15, gg = l >> 4;
        unsigned int pk[4];
        #pragma unroll
        for (int jp = 0; jp < 4; ++jp) {
            int k0 = t * 32 + gg * 8 + jp * 2;
            unsigned int lo = f2bf(W[(k0 >> 6) * 4096 + (k0 & 63) * 64 + c * 16 + rr]);
            int k1 = k0 + 1;
            unsigned int hi = f2bf(W[(k1 >> 6) * 4096 + (k1 & 63) * 64 + c * 16 + rr]);
            pk[jp] = lo | (hi << 16);
        }
        *((uint4*)&Wf[slot * 8]) = *((uint4*)pk);
    }
    __syncthreads();

    int lane = threadIdx.x & 63;
    int r = lane & 15, g = lane >> 4;
    bf16x8 bfr[4][6];
    #pragma unroll
    for (int c = 0; c < 4; ++c)
        #pragma unroll
        for (int t = 0; t < 6; ++t)
            bfr[c][t] = *((const bf16x8*)&Wf[((c * 6 + t) * 64 + lane) * 8]);

    float bl[4];
    #pragma unroll
    for (int c = 0; c < 4; ++c) bl[c] = b[c * 16 + r];

    const unsigned short* arrs[3] = {xbf, t1bf, t2bf};
    int wid = blockIdx.x * 4 + (threadIdx.x >> 6);
    int wstride = gridDim.x * 4;
    for (int tile = wid; tile < NN / 16; tile += wstride) {
        int nb = tile * 16;
        bf16x8 af[6];
        #pragma unroll
        for (int t = 0; t < 6; ++t)
            af[t] = *((const bf16x8*)(arrs[t >> 1] + (size_t)(nb + r) * 64 + (t & 1) * 32 + g * 8));
        f32x4 acc[4];
        #pragma unroll
        for (int c = 0; c < 4; ++c) acc[c] = (f32x4){bl[c], bl[c], bl[c], bl[c]};
        #pragma unroll
        for (int t = 0; t < 6; ++t)
            #pragma unroll
            for (int c = 0; c < 4; ++c)
                acc[c] = __builtin_amdgcn_mfma_f32_16x16x32_bf16(af[t], bfr[c][t], acc[c], 0, 0, 0);
        #pragma unroll
        for (int c = 0; c < 4; ++c)
            #pragma unroll
            for (int q = 0; q < 4; ++q)
                hbf[(size_t)(nb + g * 4 + q) * 64 + c * 16 + r] = f2bf(fmaxf(acc[c][q], 0.f));
    }
}

// ---- layer-2 projection via MFMA: Apre = h@(W2[0]-W2[2]) + b2 (f32);
//      Gs = bf16(dinv*[h@W2[1] | h@W2[2]]) ----
__global__ __launch_bounds__(256) void k_proj(const unsigned short* __restrict__ hbf,
                                              const float* __restrict__ W2,
                                              const float* __restrict__ b2, const float* __restrict__ dinv,
                                              float* __restrict__ Apre, unsigned short* __restrict__ Gsb) {
    __shared__ unsigned short Wf[6 * 64 * 8];   // [c*2+t][lane][8 bf16]
    for (int slot = threadIdx.x; slot < 6 * 64; slot += 256) {
        int c = slot / 128;
        int t = (slot / 64) & 1;
        int l = slot & 63;
        int rr = l & 15, gg = l >> 4;
        unsigned int pk[4];
        #pragma unroll
        for (int jp = 0; jp < 4; ++jp) {
            int k0 = t * 32 + gg * 8 + jp * 2;
            int k1 = k0 + 1;
            float w0, w1;
            if (c == 0)      { w0 = W2[k0 * 16 + rr] - W2[2048 + k0 * 16 + rr];
                               w1 = W2[k1 * 16 + rr] - W2[2048 + k1 * 16 + rr]; }
            else if (c == 1) { w0 = W2[1024 + k0 * 16 + rr]; w1 = W2[1024 + k1 * 16 + rr]; }
            else             { w0 = W2[2048 + k0 * 16 + rr]; w1 = W2[2048 + k1 * 16 + rr]; }
            pk[jp] = (unsigned int)f2bf(w0) | ((unsigned int)f2bf(w1) << 16);
        }
        *((uint4*)&Wf[slot * 8]) = *((uint4*)pk);
    }
    __syncthreads();

    int lane = threadIdx.x & 63;
    int r = lane & 15, g = lane >> 4;
    bf16x8 bfr[3][2];
    #pragma unroll
    for (int c = 0; c < 3; ++c)
        #pragma unroll
        for (int t = 0; t < 2; ++t)
            bfr[c][t] = *((const bf16x8*)&Wf[((c * 2 + t) * 64 + lane) * 8]);
    float b2r = b2[r];

    int wid = blockIdx.x * 4 + (threadIdx.x >> 6);
    int wstride = gridDim.x * 4;
    for (int tile = wid; tile < NN / 16; tile += wstride) {
        int nb = tile * 16;
        bf16x8 af[2];
        #pragma unroll
        for (int t = 0; t < 2; ++t)
            af[t] = *((const bf16x8*)(hbf + (size_t)(nb + r) * 64 + t * 32 + g * 8));
        f32x4 acc[3];
        #pragma unroll
        for (int c = 0; c < 3; ++c) acc[c] = (f32x4){0.f, 0.f, 0.f, 0.f};
        #pragma unroll
        for (int t = 0; t < 2; ++t)
            #pragma unroll
            for (int c = 0; c < 3; ++c)
                acc[c] = __builtin_amdgcn_mfma_f32_16x16x32_bf16(af[t], bfr[c][t], acc[c], 0, 0, 0);
        #pragma unroll
        for (int q = 0; q < 4; ++q) {
            int n = nb + g * 4 + q;
            float dv = dinv[n];
            Apre[(size_t)n * 16 + r] = acc[0][q] + b2r;
            Gsb[(size_t)n * 32 + r]      = f2bf(acc[1][q] * dv);
            Gsb[(size_t)n * 32 + 16 + r] = f2bf(acc[2][q] * dv);
        }
    }
}

// ---- 32-wide bf16 SpMM: q1 = P(g1) (f32); ts = bf16(dinv*P(g2)); 4 edges parallel ----
__global__ __launch_bounds__(256) void k_spmm32b(const unsigned short* __restrict__ Gsb,
                                                 float* __restrict__ q1, unsigned short* __restrict__ tsb,
                                                 const int* __restrict__ row_ptr, const int* __restrict__ cs,
                                                 const float* __restrict__ dinv) {
    int n = blockIdx.x * 4 + (threadIdx.x >> 6);
    if (n >= NN) return;
    int nu = __builtin_amdgcn_readfirstlane(n);
    int lane = threadIdx.x & 63;
    int es = lane >> 4;
    int f = lane & 15;      // feature pair 2f,2f+1 of 32
    int s = row_ptr[nu], e = row_ptr[nu + 1];
    float a0x = 0.f, a0y = 0.f, a1x = 0.f, a1y = 0.f;
    int i = s;
    for (; i + 7 < e; i += 8) {
        int c0 = cs[i + es];
        int c1 = cs[i + 4 + es];
        bf16x2 v0 = *((const bf16x2*)(Gsb + (size_t)c0 * 32 + f * 2));
        bf16x2 v1 = *((const bf16x2*)(Gsb + (size_t)c1 * 32 + f * 2));
        a0x += bf2f(v0[0]); a0y += bf2f(v0[1]);
        a1x += bf2f(v1[0]); a1y += bf2f(v1[1]);
    }
    for (; i + 3 < e; i += 4) {
        int c0 = cs[i + es];
        bf16x2 v0 = *((const bf16x2*)(Gsb + (size_t)c0 * 32 + f * 2));
        a0x += bf2f(v0[0]); a0y += bf2f(v0[1]);
    }
    if (i + es < e) {
        int c0 = cs[i + es];
        bf16x2 v0 = *((const bf16x2*)(Gsb + (size_t)c0 * 32 + f * 2));
        a0x += bf2f(v0[0]); a0y += bf2f(v0[1]);
    }
    float ax = a0x + a1x, ay = a0y + a1y;
    ax += __shfl_xor(ax, 16); ax += __shfl_xor(ax, 32);
    ay += __shfl_xor(ay, 16); ay += __shfl_xor(ay, 32);
    if (es == 0) {
        float dn = dinv[nu];
        float vx = -dn * ax, vy = -dn * ay;
        if (f < 8) {            // features 0..15 -> q1
            float2 w; w.x = vx; w.y = vy;
            *((float2*)(q1 + (size_t)nu * 16 + f * 2)) = w;
        } else {                // features 16..31 -> ts (prescaled)
            bf16x2 w; w[0] = (short)f2bf(dn * vx); w[1] = (short)f2bf(dn * vy);
            *((bf16x2*)(tsb + (size_t)nu * 16 + (f - 8) * 2)) = w;
        }
    }
}

// ---- 16-wide bf16 SpMM + combine + log_softmax; 8 edges parallel ----
__global__ __launch_bounds__(256) void k_spmm16f(const unsigned short* __restrict__ tsb,
                                                 const float* __restrict__ Apre, const float* __restrict__ q1,
                                                 const int* __restrict__ row_ptr, const int* __restrict__ cs,
                                                 const float* __restrict__ dinv, float* __restrict__ out) {
    int n = blockIdx.x * 4 + (threadIdx.x >> 6);
    if (n >= NN) return;
    int nu = __builtin_amdgcn_readfirstlane(n);
    int lane = threadIdx.x & 63;
    int es = lane >> 3;
    int f = lane & 7;       // feature pair 2f,2f+1 of 16
    int s = row_ptr[nu], e = row_ptr[nu + 1];
    float a0x = 0.f, a0y = 0.f, a1x = 0.f, a1y = 0.f;
    int i = s;
    for (; i + 15 < e; i += 16) {
        int c0 = cs[i + es];
        int c1 = cs[i + 8 + es];
        bf16x2 v0 = *((const bf16x2*)(tsb + (size_t)c0 * 16 + f * 2));
        bf16x2 v1 = *((const bf16x2*)(tsb + (size_t)c1 * 16 + f * 2));
        a0x += bf2f(v0[0]); a0y += bf2f(v0[1]);
        a1x += bf2f(v1[0]); a1y += bf2f(v1[1]);
    }
    for (; i + 7 < e; i += 8) {
        int c0 = cs[i + es];
        bf16x2 v0 = *((const bf16x2*)(tsb + (size_t)c0 * 16 + f * 2));
        a0x += bf2f(v0[0]); a0y += bf2f(v0[1]);
    }
    if (i + es < e) {
        int c0 = cs[i + es];
        bf16x2 v0 = *((const bf16x2*)(tsb + (size_t)c0 * 16 + f * 2));
        a0x += bf2f(v0[0]); a0y += bf2f(v0[1]);
    }
    float ax = a0x + a1x, ay = a0y + a1y;
    ax += __shfl_xor(ax, 8); ax += __shfl_xor(ax, 16); ax += __shfl_xor(ax, 32);
    ay += __shfl_xor(ay, 8); ay += __shfl_xor(ay, 16); ay += __shfl_xor(ay, 32);
    float dn = dinv[nu];
    float o0 = Apre[(size_t)nu * 16 + f * 2]     + q1[(size_t)nu * 16 + f * 2]     + 2.f * (-dn * ax);
    float o1 = Apre[(size_t)nu * 16 + f * 2 + 1] + q1[(size_t)nu * 16 + f * 2 + 1] + 2.f * (-dn * ay);
    float m = fmaxf(o0, o1);
    m = fmaxf(m, __shfl_xor(m, 1)); m = fmaxf(m, __shfl_xor(m, 2)); m = fmaxf(m, __shfl_xor(m, 4));
    float ssum = expf(o0 - m) + expf(o1 - m);
    ssum += __shfl_xor(ssum, 1); ssum += __shfl_xor(ssum, 2); ssum += __shfl_xor(ssum, 4);
    if (lane < 8) {
        float ls = logf(ssum);
        float2 w; w.x = o0 - m - ls; w.y = o1 - m - ls;
        *((float2*)(out + (size_t)nu * 16 + f * 2)) = w;
    }
}

extern "C" void kernel_launch(void* const* d_in, const int* in_sizes, int n_in,
                              void* d_out, int out_size, void* d_ws, size_t ws_size,
                              hipStream_t stream) {
    const float* x  = (const float*)d_in[0];
    const int*   ei = (const int*)d_in[1];
    const int*   row = ei;
    const int*   col = ei + NE;
    const float* W1 = (const float*)d_in[2];
    const float* b1 = (const float*)d_in[3];
    const float* W2 = (const float*)d_in[4];
    const float* b2 = (const float*)d_in[5];
    float* out = (float*)d_out;

    char* base = (char*)d_ws;
    size_t off = 0;
    auto alloc = [&](size_t bytes) -> char* {
        char* r = base + off;
        off = (off + bytes + 255) & ~(size_t)255;
        return r;
    };
    int*   deg        = (int*)alloc((size_t)NN * 4);
    float* dinv       = (float*)alloc((size_t)NN * 4);
    int*   row_ptr    = (int*)alloc((size_t)(NN + 1) * 4);
    int*   bsum       = (int*)alloc(512 * 4);
    int*   rank       = (int*)alloc((size_t)NE * 4);
    int*   col_sorted = (int*)alloc((size_t)NE * 4);
    unsigned short* Xbf  = (unsigned short*)alloc((size_t)NN * 64 * 2);
    unsigned short* XSbf = (unsigned short*)alloc((size_t)NN * 64 * 2);
    unsigned short* T1bf = (unsigned short*)alloc((size_t)NN * 64 * 2);
    unsigned short* T1s  = (unsigned short*)alloc((size_t)NN * 64 * 2);
    unsigned short* T2bf = (unsigned short*)alloc((size_t)NN * 64 * 2);
    unsigned short* Hbf  = (unsigned short*)alloc((size_t)NN * 64 * 2);
    float* Apre          = (float*)alloc((size_t)NN * 16 * 4);
    unsigned short* Gsb  = (unsigned short*)alloc((size_t)NN * 32 * 2);
    float* q1            = (float*)alloc((size_t)NN * 16 * 4);
    unsigned short* tsb  = (unsigned short*)alloc((size_t)NN * 16 * 2);

    hipMemsetAsync(deg, 0, (size_t)NN * 4, stream);

    int nbN  = (NN + 255) / 256;
    int nbE8 = (NE + 2047) / 2048;
    k_degrank<<<nbE8, 256, 0, stream>>>(row, deg, rank);
    k_dinv<<<nbN, 256, 0, stream>>>(deg, dinv);
    k_scale<<<(NN * 16 + 255) / 256, 256, 0, stream>>>(x, dinv, XSbf, Xbf);
    k_scan1<<<nbN, 256, 0, stream>>>(deg, row_ptr, bsum);
    k_scan2<<<1, 512, 0, stream>>>(bsum, nbN);
    k_scan3<<<nbN, 256, 0, stream>>>(deg, bsum, row_ptr);
    k_place<<<nbE8, 256, 0, stream>>>(row, col, rank, row_ptr, col_sorted);

    int nbS = (NN + 3) / 4;   // wave per node
    // layer 1 (bf16 gathers, f32 accum)
    k_spmm64b<<<nbS, 256, 0, stream>>>(XSbf, nullptr, T1bf, T1s, row_ptr, col_sorted, dinv, 0, 1);
    k_spmm64b<<<nbS, 256, 0, stream>>>(T1s, x, T2bf, nullptr, row_ptr, col_sorted, dinv, 1, 0);
    k_dense1<<<521, 256, 0, stream>>>(Xbf, T1bf, T2bf, W1, b1, Hbf);
    // layer 2: MFMA projection then narrow bf16 propagations
    k_proj<<<521, 256, 0, stream>>>(Hbf, W2, b2, dinv, Apre, Gsb);
    k_spmm32b<<<nbS, 256, 0, stream>>>(Gsb, q1, tsb, row_ptr, col_sorted, dinv);
    k_spmm16f<<<nbS, 256, 0, stream>>>(tsb, Apre, q1, row_ptr, col_sorted, dinv, out);
}

// Round 10
// 292.540 us; speedup vs baseline: 1.8410x; 1.0570x over previous
//
#include <hip/hip_runtime.h>

#define NN 100000
#define NE 1600000

typedef __attribute__((ext_vector_type(8))) short bf16x8;
typedef __attribute__((ext_vector_type(4))) short bf16x4;
typedef __attribute__((ext_vector_type(2))) short bf16x2;
typedef __attribute__((ext_vector_type(4))) float f32x4;

__device__ inline unsigned short f2bf(float f) {
    unsigned int u = __float_as_uint(f);
    return (unsigned short)((u + 0x7FFFu + ((u >> 16) & 1u)) >> 16);   // RNE bf16
}
__device__ inline float bf2f(short s) {
    return __uint_as_float(((unsigned int)(unsigned short)s) << 16);
}

// ---- degree + rank: 2 edges/thread, large grid for atomic MLP ----
__global__ void k_degrank(const int* __restrict__ row, int* __restrict__ deg, int* __restrict__ rank) {
    int base = blockIdx.x * 512 + threadIdx.x;
    int e0 = base, e1 = base + 256;
    if (e0 < NE) rank[e0] = atomicAdd(&deg[row[e0]], 1);
    if (e1 < NE) rank[e1] = atomicAdd(&deg[row[e1]], 1);
}

__global__ void k_dinv(const int* __restrict__ deg, float* __restrict__ dinv) {
    int n = blockIdx.x * 256 + threadIdx.x;
    if (n < NN) {
        int d = deg[n];
        dinv[n] = d > 0 ? rsqrtf((float)d) : 0.0f;
    }
}

// ---- bf16 copies: xbf = bf16(x), xsbf = bf16(x*dinv) ----
__global__ void k_scale(const float* __restrict__ x, const float* __restrict__ dinv,
                        unsigned short* __restrict__ xsbf, unsigned short* __restrict__ xbf) {
    int t = blockIdx.x * 256 + threadIdx.x;
    if (t < NN * 16) {
        float d = dinv[t >> 4];
        float4 v = ((const float4*)x)[t];
        bf16x4 u, s;
        u[0] = (short)f2bf(v.x); u[1] = (short)f2bf(v.y); u[2] = (short)f2bf(v.z); u[3] = (short)f2bf(v.w);
        s[0] = (short)f2bf(v.x * d); s[1] = (short)f2bf(v.y * d); s[2] = (short)f2bf(v.z * d); s[3] = (short)f2bf(v.w * d);
        ((bf16x4*)xbf)[t] = u;
        ((bf16x4*)xsbf)[t] = s;
    }
}

// ---- 3-kernel exclusive scan over deg -> row_ptr ----
__global__ void k_scan1(const int* __restrict__ deg, int* __restrict__ part, int* __restrict__ bsum) {
    __shared__ int s[256];
    int t = threadIdx.x, g = blockIdx.x * 256 + t;
    int d = (g < NN) ? deg[g] : 0;
    s[t] = d; __syncthreads();
    for (int off = 1; off < 256; off <<= 1) {
        int v = (t >= off) ? s[t - off] : 0;
        __syncthreads();
        s[t] += v;
        __syncthreads();
    }
    if (g < NN) part[g] = s[t] - d;
    if (t == 255) bsum[blockIdx.x] = s[t];
}

__global__ void k_scan2(int* __restrict__ bsum, int nb) {
    __shared__ int s[512];
    int t = threadIdx.x;
    int d = (t < nb) ? bsum[t] : 0;
    s[t] = d; __syncthreads();
    for (int off = 1; off < 512; off <<= 1) {
        int v = (t >= off) ? s[t - off] : 0;
        __syncthreads();
        s[t] += v;
        __syncthreads();
    }
    if (t < nb) bsum[t] = s[t] - d;
}

__global__ void k_scan3(const int* __restrict__ deg, const int* __restrict__ bsum,
                        int* __restrict__ row_ptr) {
    int g = blockIdx.x * 256 + threadIdx.x;
    if (g < NN) {
        int v = row_ptr[g] + bsum[g >> 8];
        row_ptr[g] = v;
        if (g == NN - 1) row_ptr[NN] = v + deg[g];
    }
}

// ---- place: no atomics, 2 edges/thread, large grid ----
__global__ void k_place(const int* __restrict__ row, const int* __restrict__ col,
                        const int* __restrict__ rank, const int* __restrict__ row_ptr,
                        int* __restrict__ col_sorted) {
    int base = blockIdx.x * 512 + threadIdx.x;
    int e0 = base, e1 = base + 256;
    if (e0 < NE) col_sorted[row_ptr[row[e0]] + rank[e0]] = col[e0];
    if (e1 < NE) col_sorted[row_ptr[row[e1]] + rank[e1]] = col[e1];
}

// ---- 64-wide bf16 SpMM: out[n] = -dinv[n]*sum_c ins[c] (+Cheb sub), f32 accum
//      8 edges in parallel (lane reads bf16x8=16B), unroll 2 -> 16 gathers in flight ----
__global__ __launch_bounds__(256) void k_spmm64b(const unsigned short* __restrict__ ins,
                                                 const unsigned short* __restrict__ subbf,
                                                 unsigned short* __restrict__ outb,
                                                 unsigned short* __restrict__ outsb,
                                                 const int* __restrict__ row_ptr, const int* __restrict__ cs,
                                                 const float* __restrict__ dinv,
                                                 int has_sub, int has_outs) {
    int n = blockIdx.x * 4 + (threadIdx.x >> 6);
    if (n >= NN) return;
    int nu = __builtin_amdgcn_readfirstlane(n);
    int lane = threadIdx.x & 63;
    int es = lane >> 3;     // edge slot 0..7
    int f = lane & 7;       // features 8f..8f+7 (16 B)
    int s = row_ptr[nu], e = row_ptr[nu + 1];
    float a0[8] = {0,0,0,0,0,0,0,0}, a1[8] = {0,0,0,0,0,0,0,0};
    int i = s;
    for (; i + 15 < e; i += 16) {
        int c0 = cs[i + es];
        int c1 = cs[i + 8 + es];
        bf16x8 v0 = *((const bf16x8*)(ins + (size_t)c0 * 64 + f * 8));
        bf16x8 v1 = *((const bf16x8*)(ins + (size_t)c1 * 64 + f * 8));
        #pragma unroll
        for (int j = 0; j < 8; ++j) { a0[j] += bf2f(v0[j]); a1[j] += bf2f(v1[j]); }
    }
    for (; i + 7 < e; i += 8) {
        int c0 = cs[i + es];
        bf16x8 v0 = *((const bf16x8*)(ins + (size_t)c0 * 64 + f * 8));
        #pragma unroll
        for (int j = 0; j < 8; ++j) a0[j] += bf2f(v0[j]);
    }
    if (i + es < e) {
        int c0 = cs[i + es];
        bf16x8 v0 = *((const bf16x8*)(ins + (size_t)c0 * 64 + f * 8));
        #pragma unroll
        for (int j = 0; j < 8; ++j) a0[j] += bf2f(v0[j]);
    }
    float a[8];
    #pragma unroll
    for (int j = 0; j < 8; ++j) {
        a[j] = a0[j] + a1[j];
        a[j] += __shfl_xor(a[j], 8);
        a[j] += __shfl_xor(a[j], 16);
        a[j] += __shfl_xor(a[j], 32);
    }
    if (es == 0) {
        float dn = dinv[nu];
        float r[8];
        #pragma unroll
        for (int j = 0; j < 8; ++j) r[j] = -dn * a[j];
        if (has_sub) {
            bf16x8 sv = *((const bf16x8*)(subbf + (size_t)nu * 64 + f * 8));
            #pragma unroll
            for (int j = 0; j < 8; ++j) r[j] = 2.f * r[j] - bf2f(sv[j]);
        }
        bf16x8 ob;
        #pragma unroll
        for (int j = 0; j < 8; ++j) ob[j] = (short)f2bf(r[j]);
        *((bf16x8*)(outb + (size_t)nu * 64 + f * 8)) = ob;
        if (has_outs) {
            bf16x8 os;
            #pragma unroll
            for (int j = 0; j < 8; ++j) os[j] = (short)f2bf(dn * r[j]);
            *((bf16x8*)(outsb + (size_t)nu * 64 + f * 8)) = os;
        }
    }
}

// ---- dense layer 1 via MFMA: hbf = relu([x|t1|t2] @ W + b), all-bf16 A stream ----
__global__ __launch_bounds__(256) void k_dense1(const unsigned short* __restrict__ xbf,
                                                const unsigned short* __restrict__ t1bf,
                                                const unsigned short* __restrict__ t2bf,
                                                const float* __restrict__ W,
                                                const float* __restrict__ b,
                                                unsigned short* __restrict__ hbf) {
    __shared__ unsigned short Wf[24 * 64 * 8];   // [c*6+t][lane][8 bf16]
    for (int slot = threadIdx.x; slot < 24 * 64; slot += 256) {
        int c = slot / 384;
        int t = (slot / 64) % 6;
        int l = slot & 63;
        int rr = l & 15, gg = l >> 4;
        unsigned int pk[4];
        #pragma unroll
        for (int jp = 0; jp < 4; ++jp) {
            int k0 = t * 32 + gg * 8 + jp * 2;
            unsigned int lo = f2bf(W[(k0 >> 6) * 4096 + (k0 & 63) * 64 + c * 16 + rr]);
            int k1 = k0 + 1;
            unsigned int hi = f2bf(W[(k1 >> 6) * 4096 + (k1 & 63) * 64 + c * 16 + rr]);
            pk[jp] = lo | (hi << 16);
        }
        *((uint4*)&Wf[slot * 8]) = *((uint4*)pk);
    }
    __syncthreads();

    int lane = threadIdx.x & 63;
    int r = lane & 15, g = lane >> 4;
    bf16x8 bfr[4][6];
    #pragma unroll
    for (int c = 0; c < 4; ++c)
        #pragma unroll
        for (int t = 0; t < 6; ++t)
            bfr[c][t] = *((const bf16x8*)&Wf[((c * 6 + t) * 64 + lane) * 8]);

    float bl[4];
    #pragma unroll
    for (int c = 0; c < 4; ++c) bl[c] = b[c * 16 + r];

    const unsigned short* arrs[3] = {xbf, t1bf, t2bf};
    int wid = blockIdx.x * 4 + (threadIdx.x >> 6);
    int wstride = gridDim.x * 4;
    for (int tile = wid; tile < NN / 16; tile += wstride) {
        int nb = tile * 16;
        bf16x8 af[6];
        #pragma unroll
        for (int t = 0; t < 6; ++t)
            af[t] = *((const bf16x8*)(arrs[t >> 1] + (size_t)(nb + r) * 64 + (t & 1) * 32 + g * 8));
        f32x4 acc[4];
        #pragma unroll
        for (int c = 0; c < 4; ++c) acc[c] = (f32x4){bl[c], bl[c], bl[c], bl[c]};
        #pragma unroll
        for (int t = 0; t < 6; ++t)
            #pragma unroll
            for (int c = 0; c < 4; ++c)
                acc[c] = __builtin_amdgcn_mfma_f32_16x16x32_bf16(af[t], bfr[c][t], acc[c], 0, 0, 0);
        #pragma unroll
        for (int c = 0; c < 4; ++c)
            #pragma unroll
            for (int q = 0; q < 4; ++q)
                hbf[(size_t)(nb + g * 4 + q) * 64 + c * 16 + r] = f2bf(fmaxf(acc[c][q], 0.f));
    }
}

// ---- layer-2 projection via MFMA: Apre = h@(W2[0]-W2[2]) + b2 (f32);
//      Gs = bf16(dinv*[h@W2[1] | h@W2[2]]) ----
__global__ __launch_bounds__(256) void k_proj(const unsigned short* __restrict__ hbf,
                                              const float* __restrict__ W2,
                                              const float* __restrict__ b2, const float* __restrict__ dinv,
                                              float* __restrict__ Apre, unsigned short* __restrict__ Gsb) {
    __shared__ unsigned short Wf[6 * 64 * 8];   // [c*2+t][lane][8 bf16]
    for (int slot = threadIdx.x; slot < 6 * 64; slot += 256) {
        int c = slot / 128;
        int t = (slot / 64) & 1;
        int l = slot & 63;
        int rr = l & 15, gg = l >> 4;
        unsigned int pk[4];
        #pragma unroll
        for (int jp = 0; jp < 4; ++jp) {
            int k0 = t * 32 + gg * 8 + jp * 2;
            int k1 = k0 + 1;
            float w0, w1;
            if (c == 0)      { w0 = W2[k0 * 16 + rr] - W2[2048 + k0 * 16 + rr];
                               w1 = W2[k1 * 16 + rr] - W2[2048 + k1 * 16 + rr]; }
            else if (c == 1) { w0 = W2[1024 + k0 * 16 + rr]; w1 = W2[1024 + k1 * 16 + rr]; }
            else             { w0 = W2[2048 + k0 * 16 + rr]; w1 = W2[2048 + k1 * 16 + rr]; }
            pk[jp] = (unsigned int)f2bf(w0) | ((unsigned int)f2bf(w1) << 16);
        }
        *((uint4*)&Wf[slot * 8]) = *((uint4*)pk);
    }
    __syncthreads();

    int lane = threadIdx.x & 63;
    int r = lane & 15, g = lane >> 4;
    bf16x8 bfr[3][2];
    #pragma unroll
    for (int c = 0; c < 3; ++c)
        #pragma unroll
        for (int t = 0; t < 2; ++t)
            bfr[c][t] = *((const bf16x8*)&Wf[((c * 2 + t) * 64 + lane) * 8]);
    float b2r = b2[r];

    int wid = blockIdx.x * 4 + (threadIdx.x >> 6);
    int wstride = gridDim.x * 4;
    for (int tile = wid; tile < NN / 16; tile += wstride) {
        int nb = tile * 16;
        bf16x8 af[2];
        #pragma unroll
        for (int t = 0; t < 2; ++t)
            af[t] = *((const bf16x8*)(hbf + (size_t)(nb + r) * 64 + t * 32 + g * 8));
        f32x4 acc[3];
        #pragma unroll
        for (int c = 0; c < 3; ++c) acc[c] = (f32x4){0.f, 0.f, 0.f, 0.f};
        #pragma unroll
        for (int t = 0; t < 2; ++t)
            #pragma unroll
            for (int c = 0; c < 3; ++c)
                acc[c] = __builtin_amdgcn_mfma_f32_16x16x32_bf16(af[t], bfr[c][t], acc[c], 0, 0, 0);
        #pragma unroll
        for (int q = 0; q < 4; ++q) {
            int n = nb + g * 4 + q;
            float dv = dinv[n];
            Apre[(size_t)n * 16 + r] = acc[0][q] + b2r;
            Gsb[(size_t)n * 32 + r]      = f2bf(acc[1][q] * dv);
            Gsb[(size_t)n * 32 + 16 + r] = f2bf(acc[2][q] * dv);
        }
    }
}

// ---- 32-wide bf16 SpMM: q1 = P(g1) (f32); ts = bf16(dinv*P(g2)); 8 edges parallel ----
__global__ __launch_bounds__(256) void k_spmm32b(const unsigned short* __restrict__ Gsb,
                                                 float* __restrict__ q1, unsigned short* __restrict__ tsb,
                                                 const int* __restrict__ row_ptr, const int* __restrict__ cs,
                                                 const float* __restrict__ dinv) {
    int n = blockIdx.x * 4 + (threadIdx.x >> 6);
    if (n >= NN) return;
    int nu = __builtin_amdgcn_readfirstlane(n);
    int lane = threadIdx.x & 63;
    int es = lane >> 3;     // edge slot 0..7
    int f = lane & 7;       // features 4f..4f+3 of 32
    int s = row_ptr[nu], e = row_ptr[nu + 1];
    float a0[4] = {0,0,0,0}, a1[4] = {0,0,0,0};
    int i = s;
    for (; i + 15 < e; i += 16) {
        int c0 = cs[i + es];
        int c1 = cs[i + 8 + es];
        bf16x4 v0 = *((const bf16x4*)(Gsb + (size_t)c0 * 32 + f * 4));
        bf16x4 v1 = *((const bf16x4*)(Gsb + (size_t)c1 * 32 + f * 4));
        #pragma unroll
        for (int j = 0; j < 4; ++j) { a0[j] += bf2f(v0[j]); a1[j] += bf2f(v1[j]); }
    }
    for (; i + 7 < e; i += 8) {
        int c0 = cs[i + es];
        bf16x4 v0 = *((const bf16x4*)(Gsb + (size_t)c0 * 32 + f * 4));
        #pragma unroll
        for (int j = 0; j < 4; ++j) a0[j] += bf2f(v0[j]);
    }
    if (i + es < e) {
        int c0 = cs[i + es];
        bf16x4 v0 = *((const bf16x4*)(Gsb + (size_t)c0 * 32 + f * 4));
        #pragma unroll
        for (int j = 0; j < 4; ++j) a0[j] += bf2f(v0[j]);
    }
    float a[4];
    #pragma unroll
    for (int j = 0; j < 4; ++j) {
        a[j] = a0[j] + a1[j];
        a[j] += __shfl_xor(a[j], 8);
        a[j] += __shfl_xor(a[j], 16);
        a[j] += __shfl_xor(a[j], 32);
    }
    if (es == 0) {
        float dn = dinv[nu];
        if (f < 4) {            // features 0..15 -> q1 (f32)
            float4 w;
            w.x = -dn * a[0]; w.y = -dn * a[1]; w.z = -dn * a[2]; w.w = -dn * a[3];
            *((float4*)(q1 + (size_t)nu * 16 + f * 4)) = w;
        } else {                // features 16..31 -> ts (prescaled bf16)
            bf16x4 w;
            #pragma unroll
            for (int j = 0; j < 4; ++j) w[j] = (short)f2bf(dn * (-dn * a[j]));
            *((bf16x4*)(tsb + (size_t)nu * 16 + (f - 4) * 4)) = w;
        }
    }
}

// ---- 16-wide bf16 SpMM + combine + log_softmax; 16 edges parallel ----
__global__ __launch_bounds__(256) void k_spmm16f(const unsigned short* __restrict__ tsb,
                                                 const float* __restrict__ Apre, const float* __restrict__ q1,
                                                 const int* __restrict__ row_ptr, const int* __restrict__ cs,
                                                 const float* __restrict__ dinv, float* __restrict__ out) {
    int n = blockIdx.x * 4 + (threadIdx.x >> 6);
    if (n >= NN) return;
    int nu = __builtin_amdgcn_readfirstlane(n);
    int lane = threadIdx.x & 63;
    int es = lane >> 2;     // edge slot 0..15
    int f = lane & 3;       // features 4f..4f+3 of 16
    int s = row_ptr[nu], e = row_ptr[nu + 1];
    float a0[4] = {0,0,0,0}, a1[4] = {0,0,0,0};
    int i = s;
    for (; i + 31 < e; i += 32) {
        int c0 = cs[i + es];
        int c1 = cs[i + 16 + es];
        bf16x4 v0 = *((const bf16x4*)(tsb + (size_t)c0 * 16 + f * 4));
        bf16x4 v1 = *((const bf16x4*)(tsb + (size_t)c1 * 16 + f * 4));
        #pragma unroll
        for (int j = 0; j < 4; ++j) { a0[j] += bf2f(v0[j]); a1[j] += bf2f(v1[j]); }
    }
    for (; i + 15 < e; i += 16) {
        int c0 = cs[i + es];
        bf16x4 v0 = *((const bf16x4*)(tsb + (size_t)c0 * 16 + f * 4));
        #pragma unroll
        for (int j = 0; j < 4; ++j) a0[j] += bf2f(v0[j]);
    }
    if (i + es < e) {
        int c0 = cs[i + es];
        bf16x4 v0 = *((const bf16x4*)(tsb + (size_t)c0 * 16 + f * 4));
        #pragma unroll
        for (int j = 0; j < 4; ++j) a0[j] += bf2f(v0[j]);
    }
    float a[4];
    #pragma unroll
    for (int j = 0; j < 4; ++j) {
        a[j] = a0[j] + a1[j];
        a[j] += __shfl_xor(a[j], 4);
        a[j] += __shfl_xor(a[j], 8);
        a[j] += __shfl_xor(a[j], 16);
        a[j] += __shfl_xor(a[j], 32);
    }
    if (es == 0) {
        float dn = dinv[nu];
        float o[4];
        #pragma unroll
        for (int j = 0; j < 4; ++j)
            o[j] = Apre[(size_t)nu * 16 + f * 4 + j] + q1[(size_t)nu * 16 + f * 4 + j]
                   + 2.f * (-dn * a[j]);
        float m = fmaxf(fmaxf(o[0], o[1]), fmaxf(o[2], o[3]));
        m = fmaxf(m, __shfl_xor(m, 1));
        m = fmaxf(m, __shfl_xor(m, 2));
        float ssum = expf(o[0] - m) + expf(o[1] - m) + expf(o[2] - m) + expf(o[3] - m);
        ssum += __shfl_xor(ssum, 1);
        ssum += __shfl_xor(ssum, 2);
        float ls = logf(ssum);
        float4 w;
        w.x = o[0] - m - ls; w.y = o[1] - m - ls; w.z = o[2] - m - ls; w.w = o[3] - m - ls;
        *((float4*)(out + (size_t)nu * 16 + f * 4)) = w;
    }
}

extern "C" void kernel_launch(void* const* d_in, const int* in_sizes, int n_in,
                              void* d_out, int out_size, void* d_ws, size_t ws_size,
                              hipStream_t stream) {
    const float* x  = (const float*)d_in[0];
    const int*   ei = (const int*)d_in[1];
    const int*   row = ei;
    const int*   col = ei + NE;
    const float* W1 = (const float*)d_in[2];
    const float* b1 = (const float*)d_in[3];
    const float* W2 = (const float*)d_in[4];
    const float* b2 = (const float*)d_in[5];
    float* out = (float*)d_out;

    char* base = (char*)d_ws;
    size_t off = 0;
    auto alloc = [&](size_t bytes) -> char* {
        char* r = base + off;
        off = (off + bytes + 255) & ~(size_t)255;
        return r;
    };
    int*   deg        = (int*)alloc((size_t)NN * 4);
    float* dinv       = (float*)alloc((size_t)NN * 4);
    int*   row_ptr    = (int*)alloc((size_t)(NN + 1) * 4);
    int*   bsum       = (int*)alloc(512 * 4);
    int*   rank       = (int*)alloc((size_t)NE * 4);
    int*   col_sorted = (int*)alloc((size_t)NE * 4);
    unsigned short* Xbf  = (unsigned short*)alloc((size_t)NN * 64 * 2);
    unsigned short* XSbf = (unsigned short*)alloc((size_t)NN * 64 * 2);
    unsigned short* T1bf = (unsigned short*)alloc((size_t)NN * 64 * 2);
    unsigned short* T1s  = (unsigned short*)alloc((size_t)NN * 64 * 2);
    unsigned short* T2bf = (unsigned short*)alloc((size_t)NN * 64 * 2);
    unsigned short* Hbf  = (unsigned short*)alloc((size_t)NN * 64 * 2);
    float* Apre          = (float*)alloc((size_t)NN * 16 * 4);
    unsigned short* Gsb  = (unsigned short*)alloc((size_t)NN * 32 * 2);
    float* q1            = (float*)alloc((size_t)NN * 16 * 4);
    unsigned short* tsb  = (unsigned short*)alloc((size_t)NN * 16 * 2);

    hipMemsetAsync(deg, 0, (size_t)NN * 4, stream);

    int nbN  = (NN + 255) / 256;
    int nbE2 = (NE + 511) / 512;   // 3125 blocks, 2 edges/thread
    k_degrank<<<nbE2, 256, 0, stream>>>(row, deg, rank);
    k_dinv<<<nbN, 256, 0, stream>>>(deg, dinv);
    k_scale<<<(NN * 16 + 255) / 256, 256, 0, stream>>>(x, dinv, XSbf, Xbf);
    k_scan1<<<nbN, 256, 0, stream>>>(deg, row_ptr, bsum);
    k_scan2<<<1, 512, 0, stream>>>(bsum, nbN);
    k_scan3<<<nbN, 256, 0, stream>>>(deg, bsum, row_ptr);
    k_place<<<nbE2, 256, 0, stream>>>(row, col, rank, row_ptr, col_sorted);

    int nbS = (NN + 3) / 4;   // wave per node
    // layer 1 (bf16 gathers, f32 accum)
    k_spmm64b<<<nbS, 256, 0, stream>>>(XSbf, nullptr, T1bf, T1s, row_ptr, col_sorted, dinv, 0, 1);
    k_spmm64b<<<nbS, 256, 0, stream>>>(T1s, Xbf, T2bf, nullptr, row_ptr, col_sorted, dinv, 1, 0);
    k_dense1<<<521, 256, 0, stream>>>(Xbf, T1bf, T2bf, W1, b1, Hbf);
    // layer 2: MFMA projection then narrow bf16 propagations
    k_proj<<<521, 256, 0, stream>>>(Hbf, W2, b2, dinv, Apre, Gsb);
    k_spmm32b<<<nbS, 256, 0, stream>>>(Gsb, q1, tsb, row_ptr, col_sorted, dinv);
    k_spmm16f<<<nbS, 256, 0, stream>>>(tsb, Apre, q1, row_ptr, col_sorted, dinv, out);
}

// Round 11
// 289.762 us; speedup vs baseline: 1.8587x; 1.0096x over previous
//
#include <hip/hip_runtime.h>

#define NN 100000
#define NE 1600000

typedef __attribute__((ext_vector_type(8))) short bf16x8;
typedef __attribute__((ext_vector_type(4))) short bf16x4;
typedef __attribute__((ext_vector_type(2))) short bf16x2;
typedef __attribute__((ext_vector_type(4))) float f32x4;

__device__ inline unsigned short f2bf(float f) {
    unsigned int u = __float_as_uint(f);
    return (unsigned short)((u + 0x7FFFu + ((u >> 16) & 1u)) >> 16);   // RNE bf16
}
__device__ inline float bf2f(short s) {
    return __uint_as_float(((unsigned int)(unsigned short)s) << 16);
}

__device__ inline unsigned get_xcc() {
    unsigned x;
    asm volatile("s_getreg_b32 %0, hwreg(HW_REG_XCC_ID)" : "=s"(x));
    return x & 7u;
}

// ---- degree + rank with XCD-privatized counters and XCD-local (workgroup-scope) atomics.
//      Only blocks on XCD k touch deg8[k*NN..], so the RMW serializes at that XCD's own L2
//      (no cross-fabric device-scope round trip). rank packs (xcc<<24)|local_rank. ----
__global__ void k_degrank(const int* __restrict__ row, int* __restrict__ deg8, int* __restrict__ rank) {
    unsigned xcc = get_xcc();
    int* mydeg = deg8 + (size_t)xcc * NN;
    int base = blockIdx.x * 512 + threadIdx.x;
    int e0 = base, e1 = base + 256;
    if (e0 < NE) {
        int lr = __hip_atomic_fetch_add(&mydeg[row[e0]], 1, __ATOMIC_RELAXED, __HIP_MEMORY_SCOPE_WORKGROUP);
        rank[e0] = lr | (int)(xcc << 24);
    }
    if (e1 < NE) {
        int lr = __hip_atomic_fetch_add(&mydeg[row[e1]], 1, __ATOMIC_RELAXED, __HIP_MEMORY_SCOPE_WORKGROUP);
        rank[e1] = lr | (int)(xcc << 24);
    }
}

// ---- bf16 copies: xbf = bf16(x), xsbf = bf16(x*dinv) ----
__global__ void k_scale(const float* __restrict__ x, const float* __restrict__ dinv,
                        unsigned short* __restrict__ xsbf, unsigned short* __restrict__ xbf) {
    int t = blockIdx.x * 256 + threadIdx.x;
    if (t < NN * 16) {
        float d = dinv[t >> 4];
        float4 v = ((const float4*)x)[t];
        bf16x4 u, s;
        u[0] = (short)f2bf(v.x); u[1] = (short)f2bf(v.y); u[2] = (short)f2bf(v.z); u[3] = (short)f2bf(v.w);
        s[0] = (short)f2bf(v.x * d); s[1] = (short)f2bf(v.y * d); s[2] = (short)f2bf(v.z * d); s[3] = (short)f2bf(v.w * d);
        ((bf16x4*)xbf)[t] = u;
        ((bf16x4*)xsbf)[t] = s;
    }
}

// ---- scan1: total deg = sum of 8 copies; block-local exclusive scan; also dinv ----
__global__ void k_scan1(const int* __restrict__ deg8, int* __restrict__ part, int* __restrict__ bsum,
                        float* __restrict__ dinv) {
    __shared__ int s[256];
    int t = threadIdx.x, g = blockIdx.x * 256 + t;
    int d = 0;
    if (g < NN) {
        #pragma unroll
        for (int x = 0; x < 8; ++x) d += deg8[(size_t)x * NN + g];
        dinv[g] = d > 0 ? rsqrtf((float)d) : 0.0f;
    }
    s[t] = d; __syncthreads();
    for (int off = 1; off < 256; off <<= 1) {
        int v = (t >= off) ? s[t - off] : 0;
        __syncthreads();
        s[t] += v;
        __syncthreads();
    }
    if (g < NN) part[g] = s[t] - d;
    if (t == 255) bsum[blockIdx.x] = s[t];
}

__global__ void k_scan2(int* __restrict__ bsum, int nb) {
    __shared__ int s[512];
    int t = threadIdx.x;
    int d = (t < nb) ? bsum[t] : 0;
    s[t] = d; __syncthreads();
    for (int off = 1; off < 512; off <<= 1) {
        int v = (t >= off) ? s[t - off] : 0;
        __syncthreads();
        s[t] += v;
        __syncthreads();
    }
    if (t < nb) bsum[t] = s[t] - d;
}

// ---- scan3: finalize row_ptr; emit per-(xcd,node) scatter bases off8 ----
__global__ void k_scan3(const int* __restrict__ deg8, const int* __restrict__ bsum,
                        int* __restrict__ row_ptr, int* __restrict__ off8) {
    int g = blockIdx.x * 256 + threadIdx.x;
    if (g < NN) {
        int v = row_ptr[g] + bsum[g >> 8];
        row_ptr[g] = v;
        int run = v, dtot = 0;
        #pragma unroll
        for (int x = 0; x < 8; ++x) {
            off8[(size_t)x * NN + g] = run;
            int c = deg8[(size_t)x * NN + g];
            run += c; dtot += c;
        }
        if (g == NN - 1) row_ptr[NN] = v + dtot;
    }
}

// ---- place: no atomics; pos = off8[xcc][row] + local_rank ----
__global__ void k_place(const int* __restrict__ row, const int* __restrict__ col,
                        const int* __restrict__ rank, const int* __restrict__ off8,
                        int* __restrict__ col_sorted) {
    int base = blockIdx.x * 512 + threadIdx.x;
    #pragma unroll
    for (int j = 0; j < 2; ++j) {
        int e = base + j * 256;
        if (e < NE) {
            int pr = rank[e];
            int x = (pr >> 24) & 7;
            int lr = pr & 0xFFFFFF;
            col_sorted[off8[(size_t)x * NN + row[e]] + lr] = col[e];
        }
    }
}

// ---- 64-wide bf16 SpMM: out[n] = -dinv[n]*sum_c ins[c] (+Cheb sub), f32 accum
//      8 edges in parallel (lane reads bf16x8=16B), unroll 2 -> 16 gathers in flight ----
__global__ __launch_bounds__(256) void k_spmm64b(const unsigned short* __restrict__ ins,
                                                 const unsigned short* __restrict__ subbf,
                                                 unsigned short* __restrict__ outb,
                                                 unsigned short* __restrict__ outsb,
                                                 const int* __restrict__ row_ptr, const int* __restrict__ cs,
                                                 const float* __restrict__ dinv,
                                                 int has_sub, int has_outs) {
    int n = blockIdx.x * 4 + (threadIdx.x >> 6);
    if (n >= NN) return;
    int nu = __builtin_amdgcn_readfirstlane(n);
    int lane = threadIdx.x & 63;
    int es = lane >> 3;     // edge slot 0..7
    int f = lane & 7;       // features 8f..8f+7 (16 B)
    int s = row_ptr[nu], e = row_ptr[nu + 1];
    float a0[8] = {0,0,0,0,0,0,0,0}, a1[8] = {0,0,0,0,0,0,0,0};
    int i = s;
    for (; i + 15 < e; i += 16) {
        int c0 = cs[i + es];
        int c1 = cs[i + 8 + es];
        bf16x8 v0 = *((const bf16x8*)(ins + (size_t)c0 * 64 + f * 8));
        bf16x8 v1 = *((const bf16x8*)(ins + (size_t)c1 * 64 + f * 8));
        #pragma unroll
        for (int j = 0; j < 8; ++j) { a0[j] += bf2f(v0[j]); a1[j] += bf2f(v1[j]); }
    }
    for (; i + 7 < e; i += 8) {
        int c0 = cs[i + es];
        bf16x8 v0 = *((const bf16x8*)(ins + (size_t)c0 * 64 + f * 8));
        #pragma unroll
        for (int j = 0; j < 8; ++j) a0[j] += bf2f(v0[j]);
    }
    if (i + es < e) {
        int c0 = cs[i + es];
        bf16x8 v0 = *((const bf16x8*)(ins + (size_t)c0 * 64 + f * 8));
        #pragma unroll
        for (int j = 0; j < 8; ++j) a0[j] += bf2f(v0[j]);
    }
    float a[8];
    #pragma unroll
    for (int j = 0; j < 8; ++j) {
        a[j] = a0[j] + a1[j];
        a[j] += __shfl_xor(a[j], 8);
        a[j] += __shfl_xor(a[j], 16);
        a[j] += __shfl_xor(a[j], 32);
    }
    if (es == 0) {
        float dn = dinv[nu];
        float r[8];
        #pragma unroll
        for (int j = 0; j < 8; ++j) r[j] = -dn * a[j];
        if (has_sub) {
            bf16x8 sv = *((const bf16x8*)(subbf + (size_t)nu * 64 + f * 8));
            #pragma unroll
            for (int j = 0; j < 8; ++j) r[j] = 2.f * r[j] - bf2f(sv[j]);
        }
        bf16x8 ob;
        #pragma unroll
        for (int j = 0; j < 8; ++j) ob[j] = (short)f2bf(r[j]);
        *((bf16x8*)(outb + (size_t)nu * 64 + f * 8)) = ob;
        if (has_outs) {
            bf16x8 os;
            #pragma unroll
            for (int j = 0; j < 8; ++j) os[j] = (short)f2bf(dn * r[j]);
            *((bf16x8*)(outsb + (size_t)nu * 64 + f * 8)) = os;
        }
    }
}

// ---- dense layer 1 via MFMA: hbf = relu([x|t1|t2] @ W + b), all-bf16 A stream ----
__global__ __launch_bounds__(256) void k_dense1(const unsigned short* __restrict__ xbf,
                                                const unsigned short* __restrict__ t1bf,
                                                const unsigned short* __restrict__ t2bf,
                                                const float* __restrict__ W,
                                                const float* __restrict__ b,
                                                unsigned short* __restrict__ hbf) {
    __shared__ unsigned short Wf[24 * 64 * 8];   // [c*6+t][lane][8 bf16]
    for (int slot = threadIdx.x; slot < 24 * 64; slot += 256) {
        int c = slot / 384;
        int t = (slot / 64) % 6;
        int l = slot & 63;
        int rr = l & 15, gg = l >> 4;
        unsigned int pk[4];
        #pragma unroll
        for (int jp = 0; jp < 4; ++jp) {
            int k0 = t * 32 + gg * 8 + jp * 2;
            unsigned int lo = f2bf(W[(k0 >> 6) * 4096 + (k0 & 63) * 64 + c * 16 + rr]);
            int k1 = k0 + 1;
            unsigned int hi = f2bf(W[(k1 >> 6) * 4096 + (k1 & 63) * 64 + c * 16 + rr]);
            pk[jp] = lo | (hi << 16);
        }
        *((uint4*)&Wf[slot * 8]) = *((uint4*)pk);
    }
    __syncthreads();

    int lane = threadIdx.x & 63;
    int r = lane & 15, g = lane >> 4;
    bf16x8 bfr[4][6];
    #pragma unroll
    for (int c = 0; c < 4; ++c)
        #pragma unroll
        for (int t = 0; t < 6; ++t)
            bfr[c][t] = *((const bf16x8*)&Wf[((c * 6 + t) * 64 + lane) * 8]);

    float bl[4];
    #pragma unroll
    for (int c = 0; c < 4; ++c) bl[c] = b[c * 16 + r];

    const unsigned short* arrs[3] = {xbf, t1bf, t2bf};
    int wid = blockIdx.x * 4 + (threadIdx.x >> 6);
    int wstride = gridDim.x * 4;
    for (int tile = wid; tile < NN / 16; tile += wstride) {
        int nb = tile * 16;
        bf16x8 af[6];
        #pragma unroll
        for (int t = 0; t < 6; ++t)
            af[t] = *((const bf16x8*)(arrs[t >> 1] + (size_t)(nb + r) * 64 + (t & 1) * 32 + g * 8));
        f32x4 acc[4];
        #pragma unroll
        for (int c = 0; c < 4; ++c) acc[c] = (f32x4){bl[c], bl[c], bl[c], bl[c]};
        #pragma unroll
        for (int t = 0; t < 6; ++t)
            #pragma unroll
            for (int c = 0; c < 4; ++c)
                acc[c] = __builtin_amdgcn_mfma_f32_16x16x32_bf16(af[t], bfr[c][t], acc[c], 0, 0, 0);
        #pragma unroll
        for (int c = 0; c < 4; ++c)
            #pragma unroll
            for (int q = 0; q < 4; ++q)
                hbf[(size_t)(nb + g * 4 + q) * 64 + c * 16 + r] = f2bf(fmaxf(acc[c][q], 0.f));
    }
}

// ---- layer-2 projection via MFMA: Apre = h@(W2[0]-W2[2]) + b2 (f32);
//      Gs = bf16(dinv*[h@W2[1] | h@W2[2]]) ----
__global__ __launch_bounds__(256) void k_proj(const unsigned short* __restrict__ hbf,
                                              const float* __restrict__ W2,
                                              const float* __restrict__ b2, const float* __restrict__ dinv,
                                              float* __restrict__ Apre, unsigned short* __restrict__ Gsb) {
    __shared__ unsigned short Wf[6 * 64 * 8];   // [c*2+t][lane][8 bf16]
    for (int slot = threadIdx.x; slot < 6 * 64; slot += 256) {
        int c = slot / 128;
        int t = (slot / 64) & 1;
        int l = slot & 63;
        int rr = l & 15, gg = l >> 4;
        unsigned int pk[4];
        #pragma unroll
        for (int jp = 0; jp < 4; ++jp) {
            int k0 = t * 32 + gg * 8 + jp * 2;
            int k1 = k0 + 1;
            float w0, w1;
            if (c == 0)      { w0 = W2[k0 * 16 + rr] - W2[2048 + k0 * 16 + rr];
                               w1 = W2[k1 * 16 + rr] - W2[2048 + k1 * 16 + rr]; }
            else if (c == 1) { w0 = W2[1024 + k0 * 16 + rr]; w1 = W2[1024 + k1 * 16 + rr]; }
            else             { w0 = W2[2048 + k0 * 16 + rr]; w1 = W2[2048 + k1 * 16 + rr]; }
            pk[jp] = (unsigned int)f2bf(w0) | ((unsigned int)f2bf(w1) << 16);
        }
        *((uint4*)&Wf[slot * 8]) = *((uint4*)pk);
    }
    __syncthreads();

    int lane = threadIdx.x & 63;
    int r = lane & 15, g = lane >> 4;
    bf16x8 bfr[3][2];
    #pragma unroll
    for (int c = 0; c < 3; ++c)
        #pragma unroll
        for (int t = 0; t < 2; ++t)
            bfr[c][t] = *((const bf16x8*)&Wf[((c * 2 + t) * 64 + lane) * 8]);
    float b2r = b2[r];

    int wid = blockIdx.x * 4 + (threadIdx.x >> 6);
    int wstride = gridDim.x * 4;
    for (int tile = wid; tile < NN / 16; tile += wstride) {
        int nb = tile * 16;
        bf16x8 af[2];
        #pragma unroll
        for (int t = 0; t < 2; ++t)
            af[t] = *((const bf16x8*)(hbf + (size_t)(nb + r) * 64 + t * 32 + g * 8));
        f32x4 acc[3];
        #pragma unroll
        for (int c = 0; c < 3; ++c) acc[c] = (f32x4){0.f, 0.f, 0.f, 0.f};
        #pragma unroll
        for (int t = 0; t < 2; ++t)
            #pragma unroll
            for (int c = 0; c < 3; ++c)
                acc[c] = __builtin_amdgcn_mfma_f32_16x16x32_bf16(af[t], bfr[c][t], acc[c], 0, 0, 0);
        #pragma unroll
        for (int q = 0; q < 4; ++q) {
            int n = nb + g * 4 + q;
            float dv = dinv[n];
            Apre[(size_t)n * 16 + r] = acc[0][q] + b2r;
            Gsb[(size_t)n * 32 + r]      = f2bf(acc[1][q] * dv);
            Gsb[(size_t)n * 32 + 16 + r] = f2bf(acc[2][q] * dv);
        }
    }
}

// ---- 32-wide bf16 SpMM: q1 = P(g1) (f32); ts = bf16(dinv*P(g2)); 8 edges parallel ----
__global__ __launch_bounds__(256) void k_spmm32b(const unsigned short* __restrict__ Gsb,
                                                 float* __restrict__ q1, unsigned short* __restrict__ tsb,
                                                 const int* __restrict__ row_ptr, const int* __restrict__ cs,
                                                 const float* __restrict__ dinv) {
    int n = blockIdx.x * 4 + (threadIdx.x >> 6);
    if (n >= NN) return;
    int nu = __builtin_amdgcn_readfirstlane(n);
    int lane = threadIdx.x & 63;
    int es = lane >> 3;     // edge slot 0..7
    int f = lane & 7;       // features 4f..4f+3 of 32
    int s = row_ptr[nu], e = row_ptr[nu + 1];
    float a0[4] = {0,0,0,0}, a1[4] = {0,0,0,0};
    int i = s;
    for (; i + 15 < e; i += 16) {
        int c0 = cs[i + es];
        int c1 = cs[i + 8 + es];
        bf16x4 v0 = *((const bf16x4*)(Gsb + (size_t)c0 * 32 + f * 4));
        bf16x4 v1 = *((const bf16x4*)(Gsb + (size_t)c1 * 32 + f * 4));
        #pragma unroll
        for (int j = 0; j < 4; ++j) { a0[j] += bf2f(v0[j]); a1[j] += bf2f(v1[j]); }
    }
    for (; i + 7 < e; i += 8) {
        int c0 = cs[i + es];
        bf16x4 v0 = *((const bf16x4*)(Gsb + (size_t)c0 * 32 + f * 4));
        #pragma unroll
        for (int j = 0; j < 4; ++j) a0[j] += bf2f(v0[j]);
    }
    if (i + es < e) {
        int c0 = cs[i + es];
        bf16x4 v0 = *((const bf16x4*)(Gsb + (size_t)c0 * 32 + f * 4));
        #pragma unroll
        for (int j = 0; j < 4; ++j) a0[j] += bf2f(v0[j]);
    }
    float a[4];
    #pragma unroll
    for (int j = 0; j < 4; ++j) {
        a[j] = a0[j] + a1[j];
        a[j] += __shfl_xor(a[j], 8);
        a[j] += __shfl_xor(a[j], 16);
        a[j] += __shfl_xor(a[j], 32);
    }
    if (es == 0) {
        float dn = dinv[nu];
        if (f < 4) {            // features 0..15 -> q1 (f32)
            float4 w;
            w.x = -dn * a[0]; w.y = -dn * a[1]; w.z = -dn * a[2]; w.w = -dn * a[3];
            *((float4*)(q1 + (size_t)nu * 16 + f * 4)) = w;
        } else {                // features 16..31 -> ts (prescaled bf16)
            bf16x4 w;
            #pragma unroll
            for (int j = 0; j < 4; ++j) w[j] = (short)f2bf(dn * (-dn * a[j]));
            *((bf16x4*)(tsb + (size_t)nu * 16 + (f - 4) * 4)) = w;
        }
    }
}

// ---- 16-wide bf16 SpMM + combine + log_softmax; 16 edges parallel ----
__global__ __launch_bounds__(256) void k_spmm16f(const unsigned short* __restrict__ tsb,
                                                 const float* __restrict__ Apre, const float* __restrict__ q1,
                                                 const int* __restrict__ row_ptr, const int* __restrict__ cs,
                                                 const float* __restrict__ dinv, float* __restrict__ out) {
    int n = blockIdx.x * 4 + (threadIdx.x >> 6);
    if (n >= NN) return;
    int nu = __builtin_amdgcn_readfirstlane(n);
    int lane = threadIdx.x & 63;
    int es = lane >> 2;     // edge slot 0..15
    int f = lane & 3;       // features 4f..4f+3 of 16
    int s = row_ptr[nu], e = row_ptr[nu + 1];
    float a0[4] = {0,0,0,0}, a1[4] = {0,0,0,0};
    int i = s;
    for (; i + 31 < e; i += 32) {
        int c0 = cs[i + es];
        int c1 = cs[i + 16 + es];
        bf16x4 v0 = *((const bf16x4*)(tsb + (size_t)c0 * 16 + f * 4));
        bf16x4 v1 = *((const bf16x4*)(tsb + (size_t)c1 * 16 + f * 4));
        #pragma unroll
        for (int j = 0; j < 4; ++j) { a0[j] += bf2f(v0[j]); a1[j] += bf2f(v1[j]); }
    }
    for (; i + 15 < e; i += 16) {
        int c0 = cs[i + es];
        bf16x4 v0 = *((const bf16x4*)(tsb + (size_t)c0 * 16 + f * 4));
        #pragma unroll
        for (int j = 0; j < 4; ++j) a0[j] += bf2f(v0[j]);
    }
    if (i + es < e) {
        int c0 = cs[i + es];
        bf16x4 v0 = *((const bf16x4*)(tsb + (size_t)c0 * 16 + f * 4));
        #pragma unroll
        for (int j = 0; j < 4; ++j) a0[j] += bf2f(v0[j]);
    }
    float a[4];
    #pragma unroll
    for (int j = 0; j < 4; ++j) {
        a[j] = a0[j] + a1[j];
        a[j] += __shfl_xor(a[j], 4);
        a[j] += __shfl_xor(a[j], 8);
        a[j] += __shfl_xor(a[j], 16);
        a[j] += __shfl_xor(a[j], 32);
    }
    if (es == 0) {
        float dn = dinv[nu];
        float o[4];
        #pragma unroll
        for (int j = 0; j < 4; ++j)
            o[j] = Apre[(size_t)nu * 16 + f * 4 + j] + q1[(size_t)nu * 16 + f * 4 + j]
                   + 2.f * (-dn * a[j]);
        float m = fmaxf(fmaxf(o[0], o[1]), fmaxf(o[2], o[3]));
        m = fmaxf(m, __shfl_xor(m, 1));
        m = fmaxf(m, __shfl_xor(m, 2));
        float ssum = expf(o[0] - m) + expf(o[1] - m) + expf(o[2] - m) + expf(o[3] - m);
        ssum += __shfl_xor(ssum, 1);
        ssum += __shfl_xor(ssum, 2);
        float ls = logf(ssum);
        float4 w;
        w.x = o[0] - m - ls; w.y = o[1] - m - ls; w.z = o[2] - m - ls; w.w = o[3] - m - ls;
        *((float4*)(out + (size_t)nu * 16 + f * 4)) = w;
    }
}

extern "C" void kernel_launch(void* const* d_in, const int* in_sizes, int n_in,
                              void* d_out, int out_size, void* d_ws, size_t ws_size,
                              hipStream_t stream) {
    const float* x  = (const float*)d_in[0];
    const int*   ei = (const int*)d_in[1];
    const int*   row = ei;
    const int*   col = ei + NE;
    const float* W1 = (const float*)d_in[2];
    const float* b1 = (const float*)d_in[3];
    const float* W2 = (const float*)d_in[4];
    const float* b2 = (const float*)d_in[5];
    float* out = (float*)d_out;

    char* base = (char*)d_ws;
    size_t off = 0;
    auto alloc = [&](size_t bytes) -> char* {
        char* r = base + off;
        off = (off + bytes + 255) & ~(size_t)255;
        return r;
    };
    int*   deg8       = (int*)alloc((size_t)8 * NN * 4);
    int*   off8       = (int*)alloc((size_t)8 * NN * 4);
    float* dinv       = (float*)alloc((size_t)NN * 4);
    int*   row_ptr    = (int*)alloc((size_t)(NN + 1) * 4);
    int*   bsum       = (int*)alloc(512 * 4);
    int*   rank       = (int*)alloc((size_t)NE * 4);
    int*   col_sorted = (int*)alloc((size_t)NE * 4);
    unsigned short* Xbf  = (unsigned short*)alloc((size_t)NN * 64 * 2);
    unsigned short* XSbf = (unsigned short*)alloc((size_t)NN * 64 * 2);
    unsigned short* T1bf = (unsigned short*)alloc((size_t)NN * 64 * 2);
    unsigned short* T1s  = (unsigned short*)alloc((size_t)NN * 64 * 2);
    unsigned short* T2bf = (unsigned short*)alloc((size_t)NN * 64 * 2);
    unsigned short* Hbf  = (unsigned short*)alloc((size_t)NN * 64 * 2);
    float* Apre          = (float*)alloc((size_t)NN * 16 * 4);
    unsigned short* Gsb  = (unsigned short*)alloc((size_t)NN * 32 * 2);
    float* q1            = (float*)alloc((size_t)NN * 16 * 4);
    unsigned short* tsb  = (unsigned short*)alloc((size_t)NN * 16 * 2);

    hipMemsetAsync(deg8, 0, (size_t)8 * NN * 4, stream);

    int nbN  = (NN + 255) / 256;
    int nbE2 = (NE + 511) / 512;   // 3125 blocks, 2 edges/thread
    k_degrank<<<nbE2, 256, 0, stream>>>(row, deg8, rank);
    k_scan1<<<nbN, 256, 0, stream>>>(deg8, row_ptr, bsum, dinv);
    k_scan2<<<1, 512, 0, stream>>>(bsum, nbN);
    k_scan3<<<nbN, 256, 0, stream>>>(deg8, bsum, row_ptr, off8);
    k_scale<<<(NN * 16 + 255) / 256, 256, 0, stream>>>(x, dinv, XSbf, Xbf);
    k_place<<<nbE2, 256, 0, stream>>>(row, col, rank, off8, col_sorted);

    int nbS = (NN + 3) / 4;   // wave per node
    // layer 1 (bf16 gathers, f32 accum)
    k_spmm64b<<<nbS, 256, 0, stream>>>(XSbf, nullptr, T1bf, T1s, row_ptr, col_sorted, dinv, 0, 1);
    k_spmm64b<<<nbS, 256, 0, stream>>>(T1s, Xbf, T2bf, nullptr, row_ptr, col_sorted, dinv, 1, 0);
    k_dense1<<<521, 256, 0, stream>>>(Xbf, T1bf, T2bf, W1, b1, Hbf);
    // layer 2: MFMA projection then narrow bf16 propagations
    k_proj<<<521, 256, 0, stream>>>(Hbf, W2, b2, dinv, Apre, Gsb);
    k_spmm32b<<<nbS, 256, 0, stream>>>(Gsb, q1, tsb, row_ptr, col_sorted, dinv);
    k_spmm16f<<<nbS, 256, 0, stream>>>(tsb, Apre, q1, row_ptr, col_sorted, dinv, out);
}

// Round 12
// 244.412 us; speedup vs baseline: 2.2035x; 1.1856x over previous
//
#include <hip/hip_runtime.h>

#define NN 100000
#define NE 1600000
#define NBUCK 196          // buckets of 512 nodes: 196*512 = 100352 >= NN
#define CAP 10240          // per-bucket capacity (mean 8192, sigma ~90 -> +22 sigma)

typedef __attribute__((ext_vector_type(8))) short bf16x8;
typedef __attribute__((ext_vector_type(4))) short bf16x4;
typedef __attribute__((ext_vector_type(4))) float f32x4;

__device__ inline unsigned short f2bf(float f) {
    unsigned int u = __float_as_uint(f);
    return (unsigned short)((u + 0x7FFFu + ((u >> 16) & 1u)) >> 16);   // RNE bf16
}
__device__ inline float bf2f(short s) {
    return __uint_as_float(((unsigned int)(unsigned short)s) << 16);
}

// ---- phase 1: bin edges into 196 node-range buckets. LDS histogram; ONE global
//      atomic per (block,bucket) = 50K total (vs 1.6M per-edge). ----
__global__ __launch_bounds__(256) void k_bin(const int* __restrict__ row, const int* __restrict__ col,
                                             int* __restrict__ gcursor, int* __restrict__ ebuf) {
    __shared__ int hist[NBUCK];
    for (int i = threadIdx.x; i < NBUCK; i += 256) hist[i] = 0;
    __syncthreads();
    int start = blockIdx.x * 6250;
    int end = start + 6250; if (end > NE) end = NE;
    for (int e = start + threadIdx.x; e < end; e += 256)
        atomicAdd(&hist[row[e] >> 9], 1);
    __syncthreads();
    for (int i = threadIdx.x; i < NBUCK; i += 256)
        hist[i] = atomicAdd(&gcursor[i], hist[i]);   // hist now = block's base in bucket
    __syncthreads();
    for (int e = start + threadIdx.x; e < end; e += 256) {
        int r = row[e], c = col[e];
        int bk = r >> 9;
        int pos = atomicAdd(&hist[bk], 1);           // LDS cursor -> global pos in bucket
        if (pos < CAP) ebuf[bk * CAP + pos] = (c << 9) | (r & 511);
    }
}

// ---- exclusive scan over bucket counts -> bstart[197]; row_ptr[NN]=NE ----
__global__ void k_bstart(const int* __restrict__ gcursor, int* __restrict__ bstart,
                         int* __restrict__ row_ptr) {
    __shared__ int s[256];
    int t = threadIdx.x;
    int d = (t < NBUCK) ? gcursor[t] : 0;
    s[t] = d; __syncthreads();
    for (int off = 1; off < 256; off <<= 1) {
        int v = (t >= off) ? s[t - off] : 0;
        __syncthreads();
        s[t] += v;
        __syncthreads();
    }
    if (t < NBUCK) bstart[t] = s[t] - d;
    if (t == NBUCK - 1) bstart[NBUCK] = s[t];
    if (t == 0) row_ptr[NN] = NE;
}

// ---- phase 2: per-bucket CSR build, all in LDS (no global atomics).
//      Also computes dinv. ----
__global__ __launch_bounds__(256) void k_build(const int* __restrict__ ebuf, const int* __restrict__ bstart,
                                               int* __restrict__ row_ptr, float* __restrict__ dinv,
                                               int* __restrict__ col_sorted) {
    __shared__ int deg[512], cur[512], ps[256];
    int b = blockIdx.x;
    int bs = bstart[b], cnt = bstart[b + 1] - bs;
    const int* eb = ebuf + (size_t)b * CAP;
    int t = threadIdx.x;
    deg[t] = 0; deg[t + 256] = 0;
    __syncthreads();
    for (int e = t; e < cnt; e += 256)
        atomicAdd(&deg[eb[e] & 511], 1);
    __syncthreads();
    int d0 = deg[2 * t], d1 = deg[2 * t + 1];
    int p = d0 + d1;
    ps[t] = p; __syncthreads();
    for (int off = 1; off < 256; off <<= 1) {
        int v = (t >= off) ? ps[t - off] : 0;
        __syncthreads();
        ps[t] += v;
        __syncthreads();
    }
    int base = bs + ps[t] - p;                  // exclusive start of node 2t
    cur[2 * t] = base; cur[2 * t + 1] = base + d0;
    int n0 = (b << 9) + 2 * t, n1 = n0 + 1;
    if (n0 < NN) { row_ptr[n0] = base;      dinv[n0] = d0 > 0 ? rsqrtf((float)d0) : 0.f; }
    if (n1 < NN) { row_ptr[n1] = base + d0; dinv[n1] = d1 > 0 ? rsqrtf((float)d1) : 0.f; }
    __syncthreads();
    for (int e = t; e < cnt; e += 256) {
        int w = eb[e];
        int pos = atomicAdd(&cur[w & 511], 1);  // LDS cursor
        col_sorted[pos] = ((unsigned)w) >> 9;
    }
}

// ---- bf16 copies: xbf = bf16(x), xsbf = bf16(x*dinv) ----
__global__ void k_scale(const float* __restrict__ x, const float* __restrict__ dinv,
                        unsigned short* __restrict__ xsbf, unsigned short* __restrict__ xbf) {
    int t = blockIdx.x * 256 + threadIdx.x;
    if (t < NN * 16) {
        float d = dinv[t >> 4];
        float4 v = ((const float4*)x)[t];
        bf16x4 u, s;
        u[0] = (short)f2bf(v.x); u[1] = (short)f2bf(v.y); u[2] = (short)f2bf(v.z); u[3] = (short)f2bf(v.w);
        s[0] = (short)f2bf(v.x * d); s[1] = (short)f2bf(v.y * d); s[2] = (short)f2bf(v.z * d); s[3] = (short)f2bf(v.w * d);
        ((bf16x4*)xbf)[t] = u;
        ((bf16x4*)xsbf)[t] = s;
    }
}

// ---- 64-wide bf16 SpMM: out[n] = -dinv[n]*sum_c ins[c] (+Cheb sub), f32 accum ----
__global__ __launch_bounds__(256) void k_spmm64b(const unsigned short* __restrict__ ins,
                                                 const unsigned short* __restrict__ subbf,
                                                 unsigned short* __restrict__ outb,
                                                 unsigned short* __restrict__ outsb,
                                                 const int* __restrict__ row_ptr, const int* __restrict__ cs,
                                                 const float* __restrict__ dinv,
                                                 int has_sub, int has_outs) {
    int n = blockIdx.x * 4 + (threadIdx.x >> 6);
    if (n >= NN) return;
    int nu = __builtin_amdgcn_readfirstlane(n);
    int lane = threadIdx.x & 63;
    int es = lane >> 3;     // edge slot 0..7
    int f = lane & 7;       // features 8f..8f+7 (16 B)
    int s = row_ptr[nu], e = row_ptr[nu + 1];
    float a0[8] = {0,0,0,0,0,0,0,0}, a1[8] = {0,0,0,0,0,0,0,0};
    int i = s;
    for (; i + 15 < e; i += 16) {
        int c0 = cs[i + es];
        int c1 = cs[i + 8 + es];
        bf16x8 v0 = *((const bf16x8*)(ins + (size_t)c0 * 64 + f * 8));
        bf16x8 v1 = *((const bf16x8*)(ins + (size_t)c1 * 64 + f * 8));
        #pragma unroll
        for (int j = 0; j < 8; ++j) { a0[j] += bf2f(v0[j]); a1[j] += bf2f(v1[j]); }
    }
    for (; i + 7 < e; i += 8) {
        int c0 = cs[i + es];
        bf16x8 v0 = *((const bf16x8*)(ins + (size_t)c0 * 64 + f * 8));
        #pragma unroll
        for (int j = 0; j < 8; ++j) a0[j] += bf2f(v0[j]);
    }
    if (i + es < e) {
        int c0 = cs[i + es];
        bf16x8 v0 = *((const bf16x8*)(ins + (size_t)c0 * 64 + f * 8));
        #pragma unroll
        for (int j = 0; j < 8; ++j) a0[j] += bf2f(v0[j]);
    }
    float a[8];
    #pragma unroll
    for (int j = 0; j < 8; ++j) {
        a[j] = a0[j] + a1[j];
        a[j] += __shfl_xor(a[j], 8);
        a[j] += __shfl_xor(a[j], 16);
        a[j] += __shfl_xor(a[j], 32);
    }
    if (es == 0) {
        float dn = dinv[nu];
        float r[8];
        #pragma unroll
        for (int j = 0; j < 8; ++j) r[j] = -dn * a[j];
        if (has_sub) {
            bf16x8 sv = *((const bf16x8*)(subbf + (size_t)nu * 64 + f * 8));
            #pragma unroll
            for (int j = 0; j < 8; ++j) r[j] = 2.f * r[j] - bf2f(sv[j]);
        }
        bf16x8 ob;
        #pragma unroll
        for (int j = 0; j < 8; ++j) ob[j] = (short)f2bf(r[j]);
        *((bf16x8*)(outb + (size_t)nu * 64 + f * 8)) = ob;
        if (has_outs) {
            bf16x8 os;
            #pragma unroll
            for (int j = 0; j < 8; ++j) os[j] = (short)f2bf(dn * r[j]);
            *((bf16x8*)(outsb + (size_t)nu * 64 + f * 8)) = os;
        }
    }
}

// ---- dense layer 1 via MFMA: hbf = relu([x|t1|t2] @ W + b) ----
__global__ __launch_bounds__(256) void k_dense1(const unsigned short* __restrict__ xbf,
                                                const unsigned short* __restrict__ t1bf,
                                                const unsigned short* __restrict__ t2bf,
                                                const float* __restrict__ W,
                                                const float* __restrict__ b,
                                                unsigned short* __restrict__ hbf) {
    __shared__ unsigned short Wf[24 * 64 * 8];   // [c*6+t][lane][8 bf16]
    for (int slot = threadIdx.x; slot < 24 * 64; slot += 256) {
        int c = slot / 384;
        int t = (slot / 64) % 6;
        int l = slot & 63;
        int rr = l & 15, gg = l >> 4;
        unsigned int pk[4];
        #pragma unroll
        for (int jp = 0; jp < 4; ++jp) {
            int k0 = t * 32 + gg * 8 + jp * 2;
            unsigned int lo = f2bf(W[(k0 >> 6) * 4096 + (k0 & 63) * 64 + c * 16 + rr]);
            int k1 = k0 + 1;
            unsigned int hi = f2bf(W[(k1 >> 6) * 4096 + (k1 & 63) * 64 + c * 16 + rr]);
            pk[jp] = lo | (hi << 16);
        }
        *((uint4*)&Wf[slot * 8]) = *((uint4*)pk);
    }
    __syncthreads();

    int lane = threadIdx.x & 63;
    int r = lane & 15, g = lane >> 4;
    bf16x8 bfr[4][6];
    #pragma unroll
    for (int c = 0; c < 4; ++c)
        #pragma unroll
        for (int t = 0; t < 6; ++t)
            bfr[c][t] = *((const bf16x8*)&Wf[((c * 6 + t) * 64 + lane) * 8]);

    float bl[4];
    #pragma unroll
    for (int c = 0; c < 4; ++c) bl[c] = b[c * 16 + r];

    const unsigned short* arrs[3] = {xbf, t1bf, t2bf};
    int wid = blockIdx.x * 4 + (threadIdx.x >> 6);
    int wstride = gridDim.x * 4;
    for (int tile = wid; tile < NN / 16; tile += wstride) {
        int nb = tile * 16;
        bf16x8 af[6];
        #pragma unroll
        for (int t = 0; t < 6; ++t)
            af[t] = *((const bf16x8*)(arrs[t >> 1] + (size_t)(nb + r) * 64 + (t & 1) * 32 + g * 8));
        f32x4 acc[4];
        #pragma unroll
        for (int c = 0; c < 4; ++c) acc[c] = (f32x4){bl[c], bl[c], bl[c], bl[c]};
        #pragma unroll
        for (int t = 0; t < 6; ++t)
            #pragma unroll
            for (int c = 0; c < 4; ++c)
                acc[c] = __builtin_amdgcn_mfma_f32_16x16x32_bf16(af[t], bfr[c][t], acc[c], 0, 0, 0);
        #pragma unroll
        for (int c = 0; c < 4; ++c)
            #pragma unroll
            for (int q = 0; q < 4; ++q)
                hbf[(size_t)(nb + g * 4 + q) * 64 + c * 16 + r] = f2bf(fmaxf(acc[c][q], 0.f));
    }
}

// ---- layer-2 projection via MFMA ----
__global__ __launch_bounds__(256) void k_proj(const unsigned short* __restrict__ hbf,
                                              const float* __restrict__ W2,
                                              const float* __restrict__ b2, const float* __restrict__ dinv,
                                              float* __restrict__ Apre, unsigned short* __restrict__ Gsb) {
    __shared__ unsigned short Wf[6 * 64 * 8];   // [c*2+t][lane][8 bf16]
    for (int slot = threadIdx.x; slot < 6 * 64; slot += 256) {
        int c = slot / 128;
        int t = (slot / 64) & 1;
        int l = slot & 63;
        int rr = l & 15, gg = l >> 4;
        unsigned int pk[4];
        #pragma unroll
        for (int jp = 0; jp < 4; ++jp) {
            int k0 = t * 32 + gg * 8 + jp * 2;
            int k1 = k0 + 1;
            float w0, w1;
            if (c == 0)      { w0 = W2[k0 * 16 + rr] - W2[2048 + k0 * 16 + rr];
                               w1 = W2[k1 * 16 + rr] - W2[2048 + k1 * 16 + rr]; }
            else if (c == 1) { w0 = W2[1024 + k0 * 16 + rr]; w1 = W2[1024 + k1 * 16 + rr]; }
            else             { w0 = W2[2048 + k0 * 16 + rr]; w1 = W2[2048 + k1 * 16 + rr]; }
            pk[jp] = (unsigned int)f2bf(w0) | ((unsigned int)f2bf(w1) << 16);
        }
        *((uint4*)&Wf[slot * 8]) = *((uint4*)pk);
    }
    __syncthreads();

    int lane = threadIdx.x & 63;
    int r = lane & 15, g = lane >> 4;
    bf16x8 bfr[3][2];
    #pragma unroll
    for (int c = 0; c < 3; ++c)
        #pragma unroll
        for (int t = 0; t < 2; ++t)
            bfr[c][t] = *((const bf16x8*)&Wf[((c * 2 + t) * 64 + lane) * 8]);
    float b2r = b2[r];

    int wid = blockIdx.x * 4 + (threadIdx.x >> 6);
    int wstride = gridDim.x * 4;
    for (int tile = wid; tile < NN / 16; tile += wstride) {
        int nb = tile * 16;
        bf16x8 af[2];
        #pragma unroll
        for (int t = 0; t < 2; ++t)
            af[t] = *((const bf16x8*)(hbf + (size_t)(nb + r) * 64 + t * 32 + g * 8));
        f32x4 acc[3];
        #pragma unroll
        for (int c = 0; c < 3; ++c) acc[c] = (f32x4){0.f, 0.f, 0.f, 0.f};
        #pragma unroll
        for (int t = 0; t < 2; ++t)
            #pragma unroll
            for (int c = 0; c < 3; ++c)
                acc[c] = __builtin_amdgcn_mfma_f32_16x16x32_bf16(af[t], bfr[c][t], acc[c], 0, 0, 0);
        #pragma unroll
        for (int q = 0; q < 4; ++q) {
            int n = nb + g * 4 + q;
            float dv = dinv[n];
            Apre[(size_t)n * 16 + r] = acc[0][q] + b2r;
            Gsb[(size_t)n * 32 + r]      = f2bf(acc[1][q] * dv);
            Gsb[(size_t)n * 32 + 16 + r] = f2bf(acc[2][q] * dv);
        }
    }
}

// ---- 32-wide bf16 SpMM: q1 = P(g1) (f32); ts = bf16(dinv*P(g2)); 8 edges parallel ----
__global__ __launch_bounds__(256) void k_spmm32b(const unsigned short* __restrict__ Gsb,
                                                 float* __restrict__ q1, unsigned short* __restrict__ tsb,
                                                 const int* __restrict__ row_ptr, const int* __restrict__ cs,
                                                 const float* __restrict__ dinv) {
    int n = blockIdx.x * 4 + (threadIdx.x >> 6);
    if (n >= NN) return;
    int nu = __builtin_amdgcn_readfirstlane(n);
    int lane = threadIdx.x & 63;
    int es = lane >> 3;     // edge slot 0..7
    int f = lane & 7;       // features 4f..4f+3 of 32
    int s = row_ptr[nu], e = row_ptr[nu + 1];
    float a0[4] = {0,0,0,0}, a1[4] = {0,0,0,0};
    int i = s;
    for (; i + 15 < e; i += 16) {
        int c0 = cs[i + es];
        int c1 = cs[i + 8 + es];
        bf16x4 v0 = *((const bf16x4*)(Gsb + (size_t)c0 * 32 + f * 4));
        bf16x4 v1 = *((const bf16x4*)(Gsb + (size_t)c1 * 32 + f * 4));
        #pragma unroll
        for (int j = 0; j < 4; ++j) { a0[j] += bf2f(v0[j]); a1[j] += bf2f(v1[j]); }
    }
    for (; i + 7 < e; i += 8) {
        int c0 = cs[i + es];
        bf16x4 v0 = *((const bf16x4*)(Gsb + (size_t)c0 * 32 + f * 4));
        #pragma unroll
        for (int j = 0; j < 4; ++j) a0[j] += bf2f(v0[j]);
    }
    if (i + es < e) {
        int c0 = cs[i + es];
        bf16x4 v0 = *((const bf16x4*)(Gsb + (size_t)c0 * 32 + f * 4));
        #pragma unroll
        for (int j = 0; j < 4; ++j) a0[j] += bf2f(v0[j]);
    }
    float a[4];
    #pragma unroll
    for (int j = 0; j < 4; ++j) {
        a[j] = a0[j] + a1[j];
        a[j] += __shfl_xor(a[j], 8);
        a[j] += __shfl_xor(a[j], 16);
        a[j] += __shfl_xor(a[j], 32);
    }
    if (es == 0) {
        float dn = dinv[nu];
        if (f < 4) {
            float4 w;
            w.x = -dn * a[0]; w.y = -dn * a[1]; w.z = -dn * a[2]; w.w = -dn * a[3];
            *((float4*)(q1 + (size_t)nu * 16 + f * 4)) = w;
        } else {
            bf16x4 w;
            #pragma unroll
            for (int j = 0; j < 4; ++j) w[j] = (short)f2bf(dn * (-dn * a[j]));
            *((bf16x4*)(tsb + (size_t)nu * 16 + (f - 4) * 4)) = w;
        }
    }
}

// ---- 16-wide bf16 SpMM + combine + log_softmax; 16 edges parallel ----
__global__ __launch_bounds__(256) void k_spmm16f(const unsigned short* __restrict__ tsb,
                                                 const float* __restrict__ Apre, const float* __restrict__ q1,
                                                 const int* __restrict__ row_ptr, const int* __restrict__ cs,
                                                 const float* __restrict__ dinv, float* __restrict__ out) {
    int n = blockIdx.x * 4 + (threadIdx.x >> 6);
    if (n >= NN) return;
    int nu = __builtin_amdgcn_readfirstlane(n);
    int lane = threadIdx.x & 63;
    int es = lane >> 2;     // edge slot 0..15
    int f = lane & 3;       // features 4f..4f+3 of 16
    int s = row_ptr[nu], e = row_ptr[nu + 1];
    float a0[4] = {0,0,0,0}, a1[4] = {0,0,0,0};
    int i = s;
    for (; i + 31 < e; i += 32) {
        int c0 = cs[i + es];
        int c1 = cs[i + 16 + es];
        bf16x4 v0 = *((const bf16x4*)(tsb + (size_t)c0 * 16 + f * 4));
        bf16x4 v1 = *((const bf16x4*)(tsb + (size_t)c1 * 16 + f * 4));
        #pragma unroll
        for (int j = 0; j < 4; ++j) { a0[j] += bf2f(v0[j]); a1[j] += bf2f(v1[j]); }
    }
    for (; i + 15 < e; i += 16) {
        int c0 = cs[i + es];
        bf16x4 v0 = *((const bf16x4*)(tsb + (size_t)c0 * 16 + f * 4));
        #pragma unroll
        for (int j = 0; j < 4; ++j) a0[j] += bf2f(v0[j]);
    }
    if (i + es < e) {
        int c0 = cs[i + es];
        bf16x4 v0 = *((const bf16x4*)(tsb + (size_t)c0 * 16 + f * 4));
        #pragma unroll
        for (int j = 0; j < 4; ++j) a0[j] += bf2f(v0[j]);
    }
    float a[4];
    #pragma unroll
    for (int j = 0; j < 4; ++j) {
        a[j] = a0[j] + a1[j];
        a[j] += __shfl_xor(a[j], 4);
        a[j] += __shfl_xor(a[j], 8);
        a[j] += __shfl_xor(a[j], 16);
        a[j] += __shfl_xor(a[j], 32);
    }
    if (es == 0) {
        float dn = dinv[nu];
        float o[4];
        #pragma unroll
        for (int j = 0; j < 4; ++j)
            o[j] = Apre[(size_t)nu * 16 + f * 4 + j] + q1[(size_t)nu * 16 + f * 4 + j]
                   + 2.f * (-dn * a[j]);
        float m = fmaxf(fmaxf(o[0], o[1]), fmaxf(o[2], o[3]));
        m = fmaxf(m, __shfl_xor(m, 1));
        m = fmaxf(m, __shfl_xor(m, 2));
        float ssum = expf(o[0] - m) + expf(o[1] - m) + expf(o[2] - m) + expf(o[3] - m);
        ssum += __shfl_xor(ssum, 1);
        ssum += __shfl_xor(ssum, 2);
        float ls = logf(ssum);
        float4 w;
        w.x = o[0] - m - ls; w.y = o[1] - m - ls; w.z = o[2] - m - ls; w.w = o[3] - m - ls;
        *((float4*)(out + (size_t)nu * 16 + f * 4)) = w;
    }
}

extern "C" void kernel_launch(void* const* d_in, const int* in_sizes, int n_in,
                              void* d_out, int out_size, void* d_ws, size_t ws_size,
                              hipStream_t stream) {
    const float* x  = (const float*)d_in[0];
    const int*   ei = (const int*)d_in[1];
    const int*   row = ei;
    const int*   col = ei + NE;
    const float* W1 = (const float*)d_in[2];
    const float* b1 = (const float*)d_in[3];
    const float* W2 = (const float*)d_in[4];
    const float* b2 = (const float*)d_in[5];
    float* out = (float*)d_out;

    char* base = (char*)d_ws;
    size_t off = 0;
    auto alloc = [&](size_t bytes) -> char* {
        char* r = base + off;
        off = (off + bytes + 255) & ~(size_t)255;
        return r;
    };
    int*   gcursor    = (int*)alloc(NBUCK * 4);
    int*   bstart     = (int*)alloc((NBUCK + 1) * 4);
    float* dinv       = (float*)alloc((size_t)NN * 4);
    int*   row_ptr    = (int*)alloc((size_t)(NN + 1) * 4);
    int*   ebuf       = (int*)alloc((size_t)NBUCK * CAP * 4);
    int*   col_sorted = (int*)alloc((size_t)NE * 4);
    unsigned short* Xbf  = (unsigned short*)alloc((size_t)NN * 64 * 2);
    unsigned short* XSbf = (unsigned short*)alloc((size_t)NN * 64 * 2);
    unsigned short* T1bf = (unsigned short*)alloc((size_t)NN * 64 * 2);
    unsigned short* T1s  = (unsigned short*)alloc((size_t)NN * 64 * 2);
    unsigned short* T2bf = (unsigned short*)alloc((size_t)NN * 64 * 2);
    unsigned short* Hbf  = (unsigned short*)alloc((size_t)NN * 64 * 2);
    float* Apre          = (float*)alloc((size_t)NN * 16 * 4);
    unsigned short* Gsb  = (unsigned short*)alloc((size_t)NN * 32 * 2);
    float* q1            = (float*)alloc((size_t)NN * 16 * 4);
    unsigned short* tsb  = (unsigned short*)alloc((size_t)NN * 16 * 2);

    hipMemsetAsync(gcursor, 0, NBUCK * 4, stream);

    // graph build: bin -> bucket starts -> per-bucket CSR (LDS atomics only)
    k_bin<<<256, 256, 0, stream>>>(row, col, gcursor, ebuf);
    k_bstart<<<1, 256, 0, stream>>>(gcursor, bstart, row_ptr);
    k_build<<<NBUCK, 256, 0, stream>>>(ebuf, bstart, row_ptr, dinv, col_sorted);
    k_scale<<<(NN * 16 + 255) / 256, 256, 0, stream>>>(x, dinv, XSbf, Xbf);

    int nbS = (NN + 3) / 4;   // wave per node
    // layer 1 (bf16 gathers, f32 accum)
    k_spmm64b<<<nbS, 256, 0, stream>>>(XSbf, nullptr, T1bf, T1s, row_ptr, col_sorted, dinv, 0, 1);
    k_spmm64b<<<nbS, 256, 0, stream>>>(T1s, Xbf, T2bf, nullptr, row_ptr, col_sorted, dinv, 1, 0);
    k_dense1<<<521, 256, 0, stream>>>(Xbf, T1bf, T2bf, W1, b1, Hbf);
    // layer 2: MFMA projection then narrow bf16 propagations
    k_proj<<<521, 256, 0, stream>>>(Hbf, W2, b2, dinv, Apre, Gsb);
    k_spmm32b<<<nbS, 256, 0, stream>>>(Gsb, q1, tsb, row_ptr, col_sorted, dinv);
    k_spmm16f<<<nbS, 256, 0, stream>>>(tsb, Apre, q1, row_ptr, col_sorted, dinv, out);
}